// Round 14
// baseline (313.708 us; speedup 1.0000x reference)
//
#include <hip/hip_runtime.h>
#include <hip/hip_bf16.h>
#include <cstdint>
#include <cstddef>

#define V_   32000
#define DS_  64
#define DF_  256
#define H_   8
#define L_   1024
#define B_   2
#define NB_  512
#define BL_  2048
#define EPS_ 1e-5f

typedef unsigned short ushort_t;
typedef unsigned int uint_t;
typedef short bf16x8 __attribute__((ext_vector_type(8)));
typedef float f32x4 __attribute__((ext_vector_type(4)));
#define AS1 __attribute__((address_space(1)))
#define AS3 __attribute__((address_space(3)))

__device__ __forceinline__ float sigmoidf_(float x) { return 1.f / (1.f + __expf(-x)); }
__device__ __forceinline__ ushort_t f2bf(float x) {
    __hip_bfloat16 b = __float2bfloat16(x);
    return __builtin_bit_cast(ushort_t, b);
}
__device__ __forceinline__ uint_t packbf(float lo, float hi) {
    return ((uint_t)f2bf(hi) << 16) | (uint_t)f2bf(lo);
}
__device__ __forceinline__ float bflo(uint_t v) {
    return __builtin_bit_cast(float, v << 16);
}
__device__ __forceinline__ float bfhi(uint_t v) {
    return __builtin_bit_cast(float, v & 0xFFFF0000u);
}

__device__ __forceinline__ float block_reduce_sum(float v, float* red) {
    int t = threadIdx.x;
    red[t] = v;
    __syncthreads();
    for (int s = 128; s > 0; s >>= 1) {
        if (t < s) red[t] += red[t + s];
        __syncthreads();
    }
    float r = red[0];
    __syncthreads();
    return r;
}

// ---------------------------------------------------------------------------
// Merged setup: weight cvt (batched 4096 floats/block) | gather | query+blob
// | combined bias.
#define NCVT_ 2180
#define NGA_  (NCVT_ + BL_)
#define NST_  (NGA_ + B_)
__global__ __launch_bounds__(256) void k_setup(
    const int* __restrict__ tok, const float* __restrict__ tok_mu,
    const float* __restrict__ tok_lv, const float* __restrict__ tok_ra,
    const float* __restrict__ tok_f, const float* __restrict__ pos_mu,
    const float* __restrict__ qproj_w, const float* __restrict__ mu_up_w,
    const float* __restrict__ mu_up_b, const float* __restrict__ ffn_w,
    const float* __restrict__ ffn_b, const float* __restrict__ agate_w,
    const float* __restrict__ agate_b, const float* __restrict__ hproj_w,
    const float* __restrict__ lm_w, const float* __restrict__ blob_mu,
    const float* __restrict__ blob_lv, const float* __restrict__ blob_ra,
    const float* __restrict__ blob_f,
    ushort_t* __restrict__ qpwbf, ushort_t* __restrict__ cwbf,
    ushort_t* __restrict__ hpwbf, ushort_t* __restrict__ wbf,
    float* __restrict__ cbias,
    float* __restrict__ mu, ushort_t* __restrict__ mub16,
    uint_t* __restrict__ muivP, float* __restrict__ alpha,
    float* __restrict__ feat, ushort_t* __restrict__ featb16,
    ushort_t* __restrict__ fTg, float* __restrict__ blobm,
    float* __restrict__ tres) {
    int blk = blockIdx.x;
    int t = threadIdx.x;
    if (blk < NCVT_) {
        const float* s = nullptr; ushort_t* dd; int base; bool cw = false;
        if (blk < 8)        { s = qproj_w; dd = qpwbf; base = blk; }
        else if (blk < 52)  { dd = cwbf; base = blk - 8; cw = true; }
        else if (blk < 180) { s = hproj_w; dd = hpwbf; base = blk - 52; }
        else                { s = lm_w; dd = wbf; base = blk - 180; }
        #pragma unroll
        for (int k = 0; k < 4; ++k) {
            int i = base * 4096 + k * 1024 + t * 4;
            float4 v = {0.f, 0.f, 0.f, 0.f};
            if (cw) {
                int r = i >> 9, c = i & 511;
                if (r < 64)        v = *reinterpret_cast<const float4*>(mu_up_w + r * 512 + c);
                else if (r < 320)  v = *reinterpret_cast<const float4*>(ffn_w + (r - 64) * 512 + c);
                else if (r == 320) v = *reinterpret_cast<const float4*>(agate_w + c);
            } else {
                v = *reinterpret_cast<const float4*>(s + i);
            }
            ushort4 o = {f2bf(v.x), f2bf(v.y), f2bf(v.z), f2bf(v.w)};
            *reinterpret_cast<ushort4*>(dd + i) = o;
        }
        return;
    }
    if (blk < NGA_) {        // gather
        int row = blk - NCVT_;
        int l = row & (L_ - 1);
        int v = tok[row];
        if (t < DS_) {
            float m = tok_mu[(size_t)v * DS_ + t] + pos_mu[l * DS_ + t];
            mu[(size_t)row * DS_ + t] = m;
            mub16[(size_t)row * DS_ + t] = f2bf(m);
            float ivv = __expf(-tok_lv[(size_t)v * DS_ + t]);
            muivP[(size_t)t * BL_ + row] = packbf(m, ivv);
        }
        float fv = tok_f[(size_t)v * DF_ + t];
        feat[(size_t)row * DF_ + t] = fv;
        featb16[(size_t)row * DF_ + t] = f2bf(fv);
        int jb = (l >> 3) & 7, jr = l & 7;
        int jp = (l & ~63) | ((jb ^ (t & 7)) << 3) | jr;
        fTg[((size_t)((row >> 10) * DF_ + t) << 10) + jp] = f2bf(fv);
        if (t == 0) alpha[row] = sigmoidf_(tok_ra[v]);
        return;
    }
    if (blk < NST_) {        // query + blob
        __shared__ float red[256];
        __shared__ int stok[L_];
        __shared__ float sq[DS_];
        __shared__ float sa[NB_];
        __shared__ float sp[NB_];
        int b = blk - NGA_;
        for (int l = t; l < L_; l += 256) stok[l] = tok[b * L_ + l];
        __syncthreads();
        int d = t & 63, c = t >> 6;
        float s = 0.f;
        for (int l = c; l < L_; l += 4)
            s += tok_mu[(size_t)stok[l] * DS_ + d] + pos_mu[l * DS_ + d];
        red[t] = s;
        __syncthreads();
        if (c == 0)
            sq[d] = (red[d] + red[64 + d] + red[128 + d] + red[192 + d]) * (1.f / L_);
        __syncthreads();
        for (int n = t; n < NB_; n += 256) {
            float d2 = 0.f;
            for (int dd = 0; dd < DS_; ++dd) {
                float diff = sq[dd] - blob_mu[n * DS_ + dd];
                d2 += __expf(-blob_lv[n * DS_ + dd]) * diff * diff;
            }
            float a = sigmoidf_(blob_ra[n]) * __expf(-0.5f * d2);
            sa[n] = a;
            sp[n] = 1.f - a;
        }
        __syncthreads();
        int n0 = t, n1 = t + 256;
        for (int s2 = 1; s2 < NB_; s2 <<= 1) {
            float t0 = (n0 >= s2) ? sp[n0 - s2] : 1.f;
            float t1 = (n1 >= s2) ? sp[n1 - s2] : 1.f;
            __syncthreads();
            sp[n0] *= t0;
            sp[n1] *= t1;
            __syncthreads();
        }
        float w0 = sa[n0] * (n0 ? sp[n0 - 1] : 1.f);
        float w1 = sa[n1] * sp[n1 - 1];
        __syncthreads();
        sa[n0] = w0;
        sa[n1] = w1;
        if (t == 0) tres[b] = sp[NB_ - 1];
        __syncthreads();
        float acc = 0.f;
        for (int n = 0; n < NB_; ++n) acc += sa[n] * blob_f[n * DF_ + t];
        blobm[b * DF_ + t] = acc;
        return;
    }
    // combined bias (352)
    for (int idx = t; idx < 352; idx += 256) {
        float bv = 0.f;
        if (idx < 64) bv = mu_up_b[idx];
        else if (idx < 320) bv = ffn_b[idx - 64];
        else if (idx == 320) bv = agate_b[0];
        cbias[idx] = bv;
    }
}

// ---------------------------------------------------------------------------
// Attention v8: TWO rows per 512-thread block, with FUSED qproj prologue
// (thread t computes q[row0][t], q[row1][t] from fp32 qproj_w, L2-resident).
__global__ __launch_bounds__(512) void k_attn8(
    const float* __restrict__ mu, const float* __restrict__ qw,
    const float* __restrict__ qb, const uint_t* __restrict__ muivP,
    const float* __restrict__ alpha, const ushort_t* __restrict__ fTg,
    ushort_t* __restrict__ mcatb) {
    __shared__ __align__(16) uint_t smiu[64 * 64];      // [d][jl]  16 KB
    __shared__ __align__(16) ushort_t sfT[256 * 64];    // [c][j']  32 KB
    __shared__ __align__(16) ushort_t sw16[16][72];     // A-tile (16 live rows)
    __shared__ float smu2[2][DS_];
    __shared__ float sqA[512], sqB[512];
    __shared__ float sT[16];
    int tid = threadIdx.x;
    int w = tid >> 6, lane = tid & 63;
    int bid = blockIdx.x;
    int b = bid >> 9;
    int i0 = (bid & 511) * 2, i1 = i0 + 1;
    int row0 = b * L_ + i0;
    const int lr = lane & 15, q4 = lane >> 4;

    if (tid < 128) smu2[tid >> 6][tid & 63] = mu[(size_t)row0 * DS_ + tid];
    __syncthreads();
    // fused qproj: q[row][t] = qb[t] + qw[t,:]·mu[row]
    {
        float qa = qb[tid], qbv = qa;
        const float4* qwr = reinterpret_cast<const float4*>(qw + (size_t)tid * DS_);
        #pragma unroll
        for (int k = 0; k < 16; ++k) {
            float4 v = qwr[k];
            qa  += v.x * smu2[0][k * 4]     + v.y * smu2[0][k * 4 + 1]
                 + v.z * smu2[0][k * 4 + 2] + v.w * smu2[0][k * 4 + 3];
            qbv += v.x * smu2[1][k * 4]     + v.y * smu2[1][k * 4 + 1]
                 + v.z * smu2[1][k * 4 + 2] + v.w * smu2[1][k * 4 + 3];
        }
        sqA[tid] = qa;
        sqB[tid] = qbv;
    }

    float T0 = 1.f, T1 = 1.f;
    f32x4 acc0 = {}, acc1 = {};

    for (int j0 = 0; j0 <= i1; j0 += 64) {
        __syncthreads();   // publish sq/sT; protect prev-chunk LDS
        if (j0 > 0) {
            bool alive = false;
            #pragma unroll
            for (int h = 0; h < 16; ++h) alive |= (sT[h] >= 1e-12f);
            if (!alive) break;
        }
        // stage muiv chunk (wave w covers d rows w*8..w*8+7)
        {
            const uint_t* src = muivP + b * L_ + j0;
            #pragma unroll
            for (int r = 0; r < 2; ++r) {
                int d = w * 8 + r * 4 + q4;
                const uint_t* gp = src + (size_t)d * BL_ + lr * 4;
                __builtin_amdgcn_global_load_lds((const AS1 uint_t*)gp,
                    (AS3 uint_t*)&smiu[(w * 8 + r * 4) * 64], 16, 0, 0);
            }
        }
        // stage feature chunk K-major: wave w covers c rows w*32..w*32+31
        {
            #pragma unroll
            for (int it = 0; it < 4; ++it) {
                int c0 = w * 32 + it * 8;
                const ushort_t* gp = fTg +
                    ((size_t)(b * DF_ + c0 + (lane >> 3)) << 10) + j0 + (lane & 7) * 8;
                __builtin_amdgcn_global_load_lds((const AS1 uint_t*)gp,
                    (AS3 uint_t*)&sfT[c0 * 64], 16, 0, 0);
            }
        }
        __syncthreads();   // stage landed

        // phase A: d2 for both rows (shared LDS read)
        int jj = j0 + lane;
        int jc = jj <= i1 ? jj : i1;
        float alv = alpha[b * L_ + jc];
        float d20 = 0.f, d21 = 0.f;
        #pragma unroll 8
        for (int d = 0; d < 64; ++d) {
            uint_t v = smiu[d * 64 + lane];
            float m = bflo(v), iv = bfhi(v);
            float f0 = sqA[w * 64 + d] - m;
            float f1 = sqB[w * 64 + d] - m;
            d20 = fmaf(iv * f0, f0, d20);
            d21 = fmaf(iv * f1, f1, d21);
        }
        float a0 = (jj <= i0) ? alv * __expf(-0.5f * d20) : 0.f;
        float a1 = (jj <= i1) ? alv * __expf(-0.5f * d21) : 0.f;

        // phase B: two wave product-scans
        float p = 1.f - a0;
        #pragma unroll
        for (int s = 1; s < 64; s <<= 1) {
            float tt = __shfl_up(p, s, 64);
            if (lane >= s) p *= tt;
        }
        float Tex = __shfl_up(p, 1, 64);
        if (lane == 0) Tex = 1.f;
        sw16[w][lane] = f2bf(a0 * T0 * Tex);
        T0 *= __shfl(p, 63, 64);

        p = 1.f - a1;
        #pragma unroll
        for (int s = 1; s < 64; s <<= 1) {
            float tt = __shfl_up(p, s, 64);
            if (lane >= s) p *= tt;
        }
        Tex = __shfl_up(p, 1, 64);
        if (lane == 0) Tex = 1.f;
        sw16[w + 8][lane] = f2bf(a1 * T1 * Tex);
        T1 *= __shfl(p, 63, 64);

        if (lane == 0) { sT[w] = T0; sT[w + 8] = T1; }
        __syncthreads();   // sw16 complete

        // phase C: PV via MFMA (wave w owns col tiles 2w, 2w+1; A fully live)
        #pragma unroll
        for (int kk = 0; kk < 2; ++kk) {
            bf16x8 afr = *reinterpret_cast<const bf16x8*>(
                (const char*)sw16 + lr * 144 + kk * 64 + q4 * 16);
            {
                int c = (w * 2 + 0) * 16 + lr;
                int bo = c * 128 + ((kk * 64 + q4 * 16) ^ ((c & 7) << 4));
                bf16x8 bfr = *reinterpret_cast<const bf16x8*>((const char*)sfT + bo);
                acc0 = __builtin_amdgcn_mfma_f32_16x16x32_bf16(afr, bfr, acc0, 0, 0, 0);
            }
            {
                int c = (w * 2 + 1) * 16 + lr;
                int bo = c * 128 + ((kk * 64 + q4 * 16) ^ ((c & 7) << 4));
                bf16x8 bfr = *reinterpret_cast<const bf16x8*>((const char*)sfT + bo);
                acc1 = __builtin_amdgcn_mfma_f32_16x16x32_bf16(afr, bfr, acc1, 0, 0, 0);
            }
        }
    }
    // epilogue: C row r -> head r&7, row-parity r>>3
    #pragma unroll
    for (int j = 0; j < 4; ++j) {
        int r = q4 * 4 + j;
        int h = r & 7, par = r >> 3;
        size_t rw = (size_t)(row0 + par) * 2048 + h * 256;
        mcatb[rw + (w * 2 + 0) * 16 + lr] = f2bf(acc0[j]);
        mcatb[rw + (w * 2 + 1) * 16 + lr] = f2bf(acc1[j]);
    }
}

// ---------------------------------------------------------------------------
// bf16 MFMA GEMM with optional XCD-chunked block swizzle (SWZ).
template <int BM, int BN, int BK, int WGM, int WGN, bool NTS, bool WB16, bool SWZ>
__global__ __launch_bounds__(256) void gemm_mfma2(
    const ushort_t* __restrict__ A, const ushort_t* __restrict__ A2, int K1,
    int strideA, const ushort_t* __restrict__ W, const float* __restrict__ bias,
    float* __restrict__ C, ushort_t* __restrict__ Cb, int M, int N, int K) {
    constexpr int WMF = BM / WGM / 16;
    constexpr int WNF = BN / WGN / 16;
    constexpr int KK  = BK / 32;
    constexpr int AHALF = BM * BK;
    constexpr int BHALF = BN * BK;
    constexpr int STAGE_B = 2 * (AHALF + BHALF) * 2;
    constexpr int EPI_B = BM * BN * 4;
    constexpr int SMEM_B = STAGE_B > EPI_B ? STAGE_B : EPI_B;
    __shared__ __align__(16) char smem[SMEM_B];
    ushort_t* As = (ushort_t*)smem;
    ushort_t* Bs = (ushort_t*)(smem + 2 * AHALF * 2);

    const int tid = threadIdx.x;
    const int wave = tid >> 6, lane = tid & 63;
    int bx = blockIdx.x, by = blockIdx.y;
    if (SWZ) {
        int nwg = gridDim.x * gridDim.y;
        int lin = by * gridDim.x + bx;
        int q = nwg >> 3, r = nwg & 7;
        int xcd = lin & 7, idx = lin >> 3;
        int nl = (xcd < r) ? (xcd * (q + 1) + idx)
                           : (r * (q + 1) + (xcd - r) * q + idx);
        bx = nl % gridDim.x;
        by = nl / gridDim.x;
    }
    const int m0 = bx * BM, n0 = by * BN;
    const int wr = wave / WGN, wc = wave % WGN;
    const int lr = lane & 15;
    const int q4 = lane >> 4;

    f32x4 acc[WMF][WNF] = {};

    auto stage = [&](int buf, int t) {
        const int k0g = t * BK;
        const ushort_t* Abase = (A2 != nullptr && k0g >= K1) ? A2 : A;
        const int kof = (A2 != nullptr && k0g >= K1) ? k0g - K1 : k0g;
        ushort_t* Ad = As + buf * AHALF;
        #pragma unroll
        for (int it = 0; it < (BM * BK / 8) / 256; ++it) {
            int cbase = it * 256 + wave * 64;
            int c = cbase + lane;
            int r = c & (BM - 1), c8 = c / BM;
            const ushort_t* gp = Abase + (size_t)(m0 + r) * strideA + kof + c8 * 8;
            __builtin_amdgcn_global_load_lds((const AS1 uint_t*)gp,
                                             (AS3 uint_t*)(Ad + cbase * 8), 16, 0, 0);
        }
        ushort_t* Bd = Bs + buf * BHALF;
        #pragma unroll
        for (int it = 0; it < (BN * BK / 8) / 256; ++it) {
            int cbase = it * 256 + wave * 64;
            int c = cbase + lane;
            int r = c & (BN - 1), c8 = c / BN;
            const ushort_t* gp = W + (size_t)(n0 + r) * K + k0g + c8 * 8;
            __builtin_amdgcn_global_load_lds((const AS1 uint_t*)gp,
                                             (AS3 uint_t*)(Bd + cbase * 8), 16, 0, 0);
        }
    };

    const int nsteps = K / BK;
    stage(0, 0);
    __syncthreads();
    for (int t = 0; t < nsteps; ++t) {
        const int cur = t & 1;
        if (t + 1 < nsteps) stage(cur ^ 1, t + 1);
        const ushort_t* Ab = As + cur * AHALF;
        const ushort_t* Bb = Bs + cur * BHALF;
        bf16x8 af[WMF][KK], bfr[WNF][KK];
        #pragma unroll
        for (int mi = 0; mi < WMF; ++mi)
            #pragma unroll
            for (int kk = 0; kk < KK; ++kk)
                af[mi][kk] = *reinterpret_cast<const bf16x8*>(
                    &Ab[((kk * 4 + q4) * BM + wr * (BM / WGM) + mi * 16 + lr) * 8]);
        #pragma unroll
        for (int ni = 0; ni < WNF; ++ni)
            #pragma unroll
            for (int kk = 0; kk < KK; ++kk)
                bfr[ni][kk] = *reinterpret_cast<const bf16x8*>(
                    &Bb[((kk * 4 + q4) * BN + wc * (BN / WGN) + ni * 16 + lr) * 8]);
        #pragma unroll
        for (int kk = 0; kk < KK; ++kk)
            #pragma unroll
            for (int mi = 0; mi < WMF; ++mi)
                #pragma unroll
                for (int ni = 0; ni < WNF; ++ni)
                    acc[mi][ni] = __builtin_amdgcn_mfma_f32_16x16x32_bf16(
                        af[mi][kk], bfr[ni][kk], acc[mi][ni], 0, 0, 0);
        __syncthreads();
    }

    float* tile = (float*)smem;
    #pragma unroll
    for (int mi = 0; mi < WMF; ++mi)
        #pragma unroll
        for (int ni = 0; ni < WNF; ++ni) {
            int col = wc * (BN / WGN) + ni * 16 + lr;
            float bv = bias[n0 + col];
            #pragma unroll
            for (int j = 0; j < 4; ++j) {
                int r2 = wr * (BM / WGM) + mi * 16 + q4 * 4 + j;
                tile[r2 * BN + col] = acc[mi][ni][j] + bv;
            }
        }
    __syncthreads();
    constexpr int EV = (BM * BN / 4) / 256;
    #pragma unroll
    for (int e = 0; e < EV; ++e) {
        int idx = e * 256 + tid;
        int r = idx / (BN / 4), c4 = idx % (BN / 4);
        f32x4 v = reinterpret_cast<const f32x4*>(tile)[idx];
        f32x4* dst = reinterpret_cast<f32x4*>(&C[(size_t)(m0 + r) * N + n0 + c4 * 4]);
        if (NTS) __builtin_nontemporal_store(v, dst);
        else *dst = v;
        if (WB16) {
            ushort4 ob = {f2bf(v[0]), f2bf(v[1]), f2bf(v[2]), f2bf(v[3])};
            *reinterpret_cast<ushort4*>(&Cb[(size_t)(m0 + r) * N + n0 + c4 * 4]) = ob;
        }
    }
}

// ---------------------------------------------------------------------------
// apply pass-0 update (elementwise; gate from dctx col 320).
__global__ __launch_bounds__(256) void k_apply(
    const float* __restrict__ dctx, float* __restrict__ mu,
    ushort_t* __restrict__ mub16, uint_t* __restrict__ muivP,
    float* __restrict__ alpha, float* __restrict__ feat,
    ushort_t* __restrict__ featb16, ushort_t* __restrict__ fTg) {
    int row = blockIdx.x, t = threadIdx.x;
    int l = row & (L_ - 1);
    const float* dr = dctx + (size_t)row * 352;
    if (t == 0) alpha[row] *= sigmoidf_(dr[320]);
    if (t < DS_) {
        float m = mu[(size_t)row * DS_ + t] + dr[t];
        mu[(size_t)row * DS_ + t] = m;
        mub16[(size_t)row * DS_ + t] = f2bf(m);
        uint_t v = muivP[(size_t)t * BL_ + row];
        muivP[(size_t)t * BL_ + row] = (v & 0xFFFF0000u) | (uint_t)f2bf(m);
    }
    float fn = feat[(size_t)row * DF_ + t] + dr[64 + t];
    feat[(size_t)row * DF_ + t] = fn;
    featb16[(size_t)row * DF_ + t] = f2bf(fn);
    int jb = (l >> 3) & 7, jr = l & 7;
    int jp = (l & ~63) | ((jb ^ (t & 7)) << 3) | jr;
    fTg[((size_t)((row >> 10) * DF_ + t) << 10) + jp] = f2bf(fn);
}

// gate + fuse + layernorm -> bf16 h.  grid BL_
__global__ __launch_bounds__(256) void k_fused_ln(
    const float* __restrict__ meaning, const float* __restrict__ blobm,
    const float* __restrict__ tres, const float* __restrict__ bgw,
    const float* __restrict__ bgb, const float* __restrict__ ln_g,
    const float* __restrict__ ln_b, ushort_t* __restrict__ houtb) {
    __shared__ float red[256];
    int row = blockIdx.x, t = threadIdx.x;
    int b = row >> 10;
    float m = meaning[(size_t)row * DF_ + t];
    float be = blobm[b * DF_ + t];
    float tr = tres[b];
    float gsum = block_reduce_sum(be * bgw[t] + m * bgw[256 + t], red);
    float gate = sigmoidf_(gsum + bgb[0]);
    float f = (1.f - tr) * gate * be + tr * m;
    float mean = block_reduce_sum(f, red) * (1.f / DF_);
    float d = f - mean;
    float var = block_reduce_sum(d * d, red) * (1.f / DF_);
    houtb[(size_t)row * DF_ + t] = f2bf(d * rsqrtf(var + EPS_) * ln_g[t] + ln_b[t]);
}

extern "C" void kernel_launch(void* const* d_in, const int* in_sizes, int n_in,
                              void* d_out, int out_size, void* d_ws, size_t ws_size,
                              hipStream_t stream) {
    const int*   tok      = (const int*)d_in[0];
    const float* tok_mu   = (const float*)d_in[1];
    const float* tok_lv   = (const float*)d_in[2];
    const float* tok_ra   = (const float*)d_in[3];
    const float* tok_f    = (const float*)d_in[4];
    const float* pos_mu   = (const float*)d_in[5];
    const float* qproj_w  = (const float*)d_in[6];
    const float* qproj_b  = (const float*)d_in[7];
    const float* hproj_w  = (const float*)d_in[8];
    const float* hproj_b  = (const float*)d_in[9];
    const float* mu_up_w  = (const float*)d_in[10];
    const float* mu_up_b  = (const float*)d_in[11];
    const float* agate_w  = (const float*)d_in[12];
    const float* agate_b  = (const float*)d_in[13];
    const float* ffn_w    = (const float*)d_in[14];
    const float* ffn_b    = (const float*)d_in[15];
    const float* ln_g     = (const float*)d_in[16];
    const float* ln_b     = (const float*)d_in[17];
    const float* lm_w     = (const float*)d_in[18];
    const float* lm_b     = (const float*)d_in[19];
    const float* blob_mu  = (const float*)d_in[20];
    const float* blob_lv  = (const float*)d_in[21];
    const float* blob_ra  = (const float*)d_in[22];
    const float* blob_f   = (const float*)d_in[23];
    const float* bgate_w  = (const float*)d_in[24];
    const float* bgate_b  = (const float*)d_in[25];
    float* out = (float*)d_out;

    float* ws = (float*)d_ws;
    float* mu      = ws;                        // BL*64
    float* alpha   = mu + BL_ * DS_;            // BL
    float* feat    = alpha + BL_;               // BL*256
    float* blobm   = feat + BL_ * DF_;          // B*256
    float* tres    = blobm + B_ * DF_;          // pad 64
    float* meaning = tres + 64;                 // BL*256
    float* dctx    = meaning + BL_ * DF_;       // BL*352
    float* cbias   = dctx + (size_t)BL_ * 352;  // 352 (pad 384)
    uint_t* muivP  = (uint_t*)(cbias + 384);              // 64*BL
    ushort_t* fTg   = (ushort_t*)(muivP + (size_t)DS_ * BL_); // B*256*1024
    ushort_t* mub16 = fTg + (size_t)B_ * DF_ * L_;        // BL*64
    ushort_t* featb16 = mub16 + (size_t)BL_ * DS_;        // BL*256
    ushort_t* meanb16 = featb16 + (size_t)BL_ * DF_;      // BL*256
    ushort_t* mcatb = meanb16 + (size_t)BL_ * DF_;        // BL*2048
    ushort_t* hbufb = mcatb + (size_t)BL_ * 2048;         // BL*256
    ushort_t* wbf   = hbufb + (size_t)BL_ * DF_;          // V*256
    ushort_t* hpwbf = wbf + (size_t)V_ * DF_;             // 256*2048
    ushort_t* qpwbf = hpwbf + (size_t)DF_ * 2048;         // 512*64
    ushort_t* cwbf  = qpwbf + (size_t)512 * 64;           // 352*512

    k_setup<<<NST_ + 1, 256, 0, stream>>>(
        tok, tok_mu, tok_lv, tok_ra, tok_f, pos_mu,
        qproj_w, mu_up_w, mu_up_b, ffn_w, ffn_b, agate_w, agate_b,
        hproj_w, lm_w, blob_mu, blob_lv, blob_ra, blob_f,
        qpwbf, cwbf, hpwbf, wbf, cbias,
        mu, mub16, muivP, alpha, feat, featb16, fTg, blobm, tres);

    for (int p = 0; p < 2; ++p) {
        k_attn8<<<B_ * L_ / 2, 512, 0, stream>>>(mu, qproj_w, qproj_b, muivP,
                                                 alpha, fTg, mcatb);
        if (p == 0) {
            gemm_mfma2<32, 32, 128, 2, 2, false, true, false>
                <<<dim3(BL_ / 32, DF_ / 32), 256, 0, stream>>>(
                mcatb, nullptr, 0, H_ * DF_, hpwbf, hproj_b, meaning, meanb16,
                BL_, DF_, H_ * DF_);
            gemm_mfma2<32, 32, 128, 2, 2, false, false, false>
                <<<dim3(BL_ / 32, 352 / 32), 256, 0, stream>>>(
                featb16, meanb16, DF_, DF_, cwbf, cbias, dctx, nullptr,
                BL_, 352, 512);
            k_apply<<<BL_, 256, 0, stream>>>(dctx, mu, mub16, muivP, alpha,
                                             feat, featb16, fTg);
        } else {
            gemm_mfma2<32, 32, 128, 2, 2, false, false, false>
                <<<dim3(BL_ / 32, DF_ / 32), 256, 0, stream>>>(
                mcatb, nullptr, 0, H_ * DF_, hpwbf, hproj_b, meaning, nullptr,
                BL_, DF_, H_ * DF_);
        }
    }

    k_fused_ln<<<BL_, 256, 0, stream>>>(meaning, blobm, tres, bgate_w, bgate_b,
                                        ln_g, ln_b, hbufb);
    gemm_mfma2<128, 128, 64, 2, 2, true, false, true>
        <<<dim3(BL_ / 128, V_ / 128), 256, 0, stream>>>(
        hbufb, nullptr, 0, DF_, wbf, lm_b, out, nullptr, BL_, V_, DF_);
}

// Round 15
// 299.415 us; speedup vs baseline: 1.0477x; 1.0477x over previous
//
#include <hip/hip_runtime.h>
#include <hip/hip_bf16.h>
#include <cstdint>
#include <cstddef>

#define V_   32000
#define DS_  64
#define DF_  256
#define H_   8
#define L_   1024
#define B_   2
#define NB_  512
#define BL_  2048
#define EPS_ 1e-5f

typedef unsigned short ushort_t;
typedef unsigned int uint_t;
typedef short bf16x8 __attribute__((ext_vector_type(8)));
typedef float f32x4 __attribute__((ext_vector_type(4)));
#define AS1 __attribute__((address_space(1)))
#define AS3 __attribute__((address_space(3)))

__device__ __forceinline__ float sigmoidf_(float x) { return 1.f / (1.f + __expf(-x)); }
__device__ __forceinline__ ushort_t f2bf(float x) {
    __hip_bfloat16 b = __float2bfloat16(x);
    return __builtin_bit_cast(ushort_t, b);
}
__device__ __forceinline__ uint_t packbf(float lo, float hi) {
    return ((uint_t)f2bf(hi) << 16) | (uint_t)f2bf(lo);
}
__device__ __forceinline__ float bflo(uint_t v) {
    return __builtin_bit_cast(float, v << 16);
}
__device__ __forceinline__ float bfhi(uint_t v) {
    return __builtin_bit_cast(float, v & 0xFFFF0000u);
}

__device__ __forceinline__ float block_reduce_sum(float v, float* red) {
    int t = threadIdx.x;
    red[t] = v;
    __syncthreads();
    for (int s = 128; s > 0; s >>= 1) {
        if (t < s) red[t] += red[t + s];
        __syncthreads();
    }
    float r = red[0];
    __syncthreads();
    return r;
}

// ---------------------------------------------------------------------------
// Merged setup: weight cvt (batched 4096 floats/block) | gather | query+blob
// | combined bias.
#define NCVT_ 2180
#define NGA_  (NCVT_ + BL_)
#define NST_  (NGA_ + B_)
__global__ __launch_bounds__(256) void k_setup(
    const int* __restrict__ tok, const float* __restrict__ tok_mu,
    const float* __restrict__ tok_lv, const float* __restrict__ tok_ra,
    const float* __restrict__ tok_f, const float* __restrict__ pos_mu,
    const float* __restrict__ qproj_w, const float* __restrict__ mu_up_w,
    const float* __restrict__ mu_up_b, const float* __restrict__ ffn_w,
    const float* __restrict__ ffn_b, const float* __restrict__ agate_w,
    const float* __restrict__ agate_b, const float* __restrict__ hproj_w,
    const float* __restrict__ lm_w, const float* __restrict__ blob_mu,
    const float* __restrict__ blob_lv, const float* __restrict__ blob_ra,
    const float* __restrict__ blob_f,
    ushort_t* __restrict__ qpwbf, ushort_t* __restrict__ cwbf,
    ushort_t* __restrict__ hpwbf, ushort_t* __restrict__ wbf,
    float* __restrict__ cbias,
    float* __restrict__ mu, ushort_t* __restrict__ mub16,
    uint_t* __restrict__ muivP, float* __restrict__ alpha,
    float* __restrict__ feat, ushort_t* __restrict__ featb16,
    ushort_t* __restrict__ fTg, float* __restrict__ blobm,
    float* __restrict__ tres) {
    int blk = blockIdx.x;
    int t = threadIdx.x;
    if (blk < NCVT_) {
        const float* s = nullptr; ushort_t* dd; int base; bool cw = false;
        if (blk < 8)        { s = qproj_w; dd = qpwbf; base = blk; }
        else if (blk < 52)  { dd = cwbf; base = blk - 8; cw = true; }
        else if (blk < 180) { s = hproj_w; dd = hpwbf; base = blk - 52; }
        else                { s = lm_w; dd = wbf; base = blk - 180; }
        #pragma unroll
        for (int k = 0; k < 4; ++k) {
            int i = base * 4096 + k * 1024 + t * 4;
            float4 v = {0.f, 0.f, 0.f, 0.f};
            if (cw) {
                int r = i >> 9, c = i & 511;
                if (r < 64)        v = *reinterpret_cast<const float4*>(mu_up_w + r * 512 + c);
                else if (r < 320)  v = *reinterpret_cast<const float4*>(ffn_w + (r - 64) * 512 + c);
                else if (r == 320) v = *reinterpret_cast<const float4*>(agate_w + c);
            } else {
                v = *reinterpret_cast<const float4*>(s + i);
            }
            ushort4 o = {f2bf(v.x), f2bf(v.y), f2bf(v.z), f2bf(v.w)};
            *reinterpret_cast<ushort4*>(dd + i) = o;
        }
        return;
    }
    if (blk < NGA_) {        // gather
        int row = blk - NCVT_;
        int l = row & (L_ - 1);
        int v = tok[row];
        if (t < DS_) {
            float m = tok_mu[(size_t)v * DS_ + t] + pos_mu[l * DS_ + t];
            mu[(size_t)row * DS_ + t] = m;
            mub16[(size_t)row * DS_ + t] = f2bf(m);
            float ivv = __expf(-tok_lv[(size_t)v * DS_ + t]);
            muivP[(size_t)t * BL_ + row] = packbf(m, ivv);
        }
        float fv = tok_f[(size_t)v * DF_ + t];
        feat[(size_t)row * DF_ + t] = fv;
        featb16[(size_t)row * DF_ + t] = f2bf(fv);
        int jb = (l >> 3) & 7, jr = l & 7;
        int jp = (l & ~63) | ((jb ^ (t & 7)) << 3) | jr;
        fTg[((size_t)((row >> 10) * DF_ + t) << 10) + jp] = f2bf(fv);
        if (t == 0) alpha[row] = sigmoidf_(tok_ra[v]);
        return;
    }
    if (blk < NST_) {        // query + blob
        __shared__ float red[256];
        __shared__ int stok[L_];
        __shared__ float sq[DS_];
        __shared__ float sa[NB_];
        __shared__ float sp[NB_];
        int b = blk - NGA_;
        for (int l = t; l < L_; l += 256) stok[l] = tok[b * L_ + l];
        __syncthreads();
        int d = t & 63, c = t >> 6;
        float s = 0.f;
        for (int l = c; l < L_; l += 4)
            s += tok_mu[(size_t)stok[l] * DS_ + d] + pos_mu[l * DS_ + d];
        red[t] = s;
        __syncthreads();
        if (c == 0)
            sq[d] = (red[d] + red[64 + d] + red[128 + d] + red[192 + d]) * (1.f / L_);
        __syncthreads();
        for (int n = t; n < NB_; n += 256) {
            float d2 = 0.f;
            for (int dd = 0; dd < DS_; ++dd) {
                float diff = sq[dd] - blob_mu[n * DS_ + dd];
                d2 += __expf(-blob_lv[n * DS_ + dd]) * diff * diff;
            }
            float a = sigmoidf_(blob_ra[n]) * __expf(-0.5f * d2);
            sa[n] = a;
            sp[n] = 1.f - a;
        }
        __syncthreads();
        int n0 = t, n1 = t + 256;
        for (int s2 = 1; s2 < NB_; s2 <<= 1) {
            float t0 = (n0 >= s2) ? sp[n0 - s2] : 1.f;
            float t1 = (n1 >= s2) ? sp[n1 - s2] : 1.f;
            __syncthreads();
            sp[n0] *= t0;
            sp[n1] *= t1;
            __syncthreads();
        }
        float w0 = sa[n0] * (n0 ? sp[n0 - 1] : 1.f);
        float w1 = sa[n1] * sp[n1 - 1];
        __syncthreads();
        sa[n0] = w0;
        sa[n1] = w1;
        if (t == 0) tres[b] = sp[NB_ - 1];
        __syncthreads();
        float acc = 0.f;
        for (int n = 0; n < NB_; ++n) acc += sa[n] * blob_f[n * DF_ + t];
        blobm[b * DF_ + t] = acc;
        return;
    }
    // combined bias (352)
    for (int idx = t; idx < 352; idx += 256) {
        float bv = 0.f;
        if (idx < 64) bv = mu_up_b[idx];
        else if (idx < 320) bv = ffn_b[idx - 64];
        else if (idx == 320) bv = agate_b[0];
        cbias[idx] = bv;
    }
}

// ---------------------------------------------------------------------------
// Attention v7: TWO rows (i0, i0+1) per 512-thread block (r11/r12, verified).
__global__ __launch_bounds__(512) void k_attn7(
    const float* __restrict__ q, const uint_t* __restrict__ muivP,
    const float* __restrict__ alpha, const ushort_t* __restrict__ fTg,
    ushort_t* __restrict__ mcatb) {
    __shared__ __align__(16) uint_t smiu[64 * 64];      // [d][jl]  16 KB
    __shared__ __align__(16) ushort_t sfT[256 * 64];    // [c][j']  32 KB
    __shared__ __align__(16) ushort_t sw16[16][72];     // A-tile (16 live rows)
    __shared__ float sqA[512], sqB[512];
    __shared__ float sT[16];
    int tid = threadIdx.x;
    int w = tid >> 6, lane = tid & 63;
    int bid = blockIdx.x;
    int b = bid >> 9;
    int i0 = (bid & 511) * 2, i1 = i0 + 1;
    int row0 = b * L_ + i0;
    const int lr = lane & 15, q4 = lane >> 4;

    sqA[tid] = q[(size_t)row0 * 512 + tid];
    sqB[tid] = q[(size_t)(row0 + 1) * 512 + tid];

    float T0 = 1.f, T1 = 1.f;
    f32x4 acc0 = {}, acc1 = {};

    for (int j0 = 0; j0 <= i1; j0 += 64) {
        __syncthreads();   // publish sq/sT; protect prev-chunk LDS
        if (j0 > 0) {
            bool alive = false;
            #pragma unroll
            for (int h = 0; h < 16; ++h) alive |= (sT[h] >= 1e-12f);
            if (!alive) break;
        }
        // stage muiv chunk (wave w covers d rows w*8..w*8+7)
        {
            const uint_t* src = muivP + b * L_ + j0;
            #pragma unroll
            for (int r = 0; r < 2; ++r) {
                int d = w * 8 + r * 4 + q4;
                const uint_t* gp = src + (size_t)d * BL_ + lr * 4;
                __builtin_amdgcn_global_load_lds((const AS1 uint_t*)gp,
                    (AS3 uint_t*)&smiu[(w * 8 + r * 4) * 64], 16, 0, 0);
            }
        }
        // stage feature chunk K-major: wave w covers c rows w*32..w*32+31
        {
            #pragma unroll
            for (int it = 0; it < 4; ++it) {
                int c0 = w * 32 + it * 8;
                const ushort_t* gp = fTg +
                    ((size_t)(b * DF_ + c0 + (lane >> 3)) << 10) + j0 + (lane & 7) * 8;
                __builtin_amdgcn_global_load_lds((const AS1 uint_t*)gp,
                    (AS3 uint_t*)&sfT[c0 * 64], 16, 0, 0);
            }
        }
        __syncthreads();   // stage landed

        // phase A: d2 for both rows (shared LDS read)
        int jj = j0 + lane;
        int jc = jj <= i1 ? jj : i1;
        float alv = alpha[b * L_ + jc];
        float d20 = 0.f, d21 = 0.f;
        #pragma unroll 8
        for (int d = 0; d < 64; ++d) {
            uint_t v = smiu[d * 64 + lane];
            float m = bflo(v), iv = bfhi(v);
            float f0 = sqA[w * 64 + d] - m;
            float f1 = sqB[w * 64 + d] - m;
            d20 = fmaf(iv * f0, f0, d20);
            d21 = fmaf(iv * f1, f1, d21);
        }
        float a0 = (jj <= i0) ? alv * __expf(-0.5f * d20) : 0.f;
        float a1 = (jj <= i1) ? alv * __expf(-0.5f * d21) : 0.f;

        // phase B: two wave product-scans
        float p = 1.f - a0;
        #pragma unroll
        for (int s = 1; s < 64; s <<= 1) {
            float tt = __shfl_up(p, s, 64);
            if (lane >= s) p *= tt;
        }
        float Tex = __shfl_up(p, 1, 64);
        if (lane == 0) Tex = 1.f;
        sw16[w][lane] = f2bf(a0 * T0 * Tex);
        T0 *= __shfl(p, 63, 64);

        p = 1.f - a1;
        #pragma unroll
        for (int s = 1; s < 64; s <<= 1) {
            float tt = __shfl_up(p, s, 64);
            if (lane >= s) p *= tt;
        }
        Tex = __shfl_up(p, 1, 64);
        if (lane == 0) Tex = 1.f;
        sw16[w + 8][lane] = f2bf(a1 * T1 * Tex);
        T1 *= __shfl(p, 63, 64);

        if (lane == 0) { sT[w] = T0; sT[w + 8] = T1; }
        __syncthreads();   // sw16 complete

        // phase C: PV via MFMA (wave w owns col tiles 2w, 2w+1; A fully live)
        #pragma unroll
        for (int kk = 0; kk < 2; ++kk) {
            bf16x8 afr = *reinterpret_cast<const bf16x8*>(
                (const char*)sw16 + lr * 144 + kk * 64 + q4 * 16);
            {
                int c = (w * 2 + 0) * 16 + lr;
                int bo = c * 128 + ((kk * 64 + q4 * 16) ^ ((c & 7) << 4));
                bf16x8 bfr = *reinterpret_cast<const bf16x8*>((const char*)sfT + bo);
                acc0 = __builtin_amdgcn_mfma_f32_16x16x32_bf16(afr, bfr, acc0, 0, 0, 0);
            }
            {
                int c = (w * 2 + 1) * 16 + lr;
                int bo = c * 128 + ((kk * 64 + q4 * 16) ^ ((c & 7) << 4));
                bf16x8 bfr = *reinterpret_cast<const bf16x8*>((const char*)sfT + bo);
                acc1 = __builtin_amdgcn_mfma_f32_16x16x32_bf16(afr, bfr, acc1, 0, 0, 0);
            }
        }
    }
    // epilogue: C row r -> head r&7, row-parity r>>3
    #pragma unroll
    for (int j = 0; j < 4; ++j) {
        int r = q4 * 4 + j;
        int h = r & 7, par = r >> 3;
        size_t rw = (size_t)(row0 + par) * 2048 + h * 256;
        mcatb[rw + (w * 2 + 0) * 16 + lr] = f2bf(acc0[j]);
        mcatb[rw + (w * 2 + 1) * 16 + lr] = f2bf(acc1[j]);
    }
}

// ---------------------------------------------------------------------------
// bf16 MFMA GEMM with optional XCD-chunked block swizzle (SWZ).
template <int BM, int BN, int BK, int WGM, int WGN, bool NTS, bool WB16, bool SWZ>
__global__ __launch_bounds__(256) void gemm_mfma2(
    const ushort_t* __restrict__ A, const ushort_t* __restrict__ A2, int K1,
    int strideA, const ushort_t* __restrict__ W, const float* __restrict__ bias,
    float* __restrict__ C, ushort_t* __restrict__ Cb, int M, int N, int K) {
    constexpr int WMF = BM / WGM / 16;
    constexpr int WNF = BN / WGN / 16;
    constexpr int KK  = BK / 32;
    constexpr int AHALF = BM * BK;
    constexpr int BHALF = BN * BK;
    constexpr int STAGE_B = 2 * (AHALF + BHALF) * 2;
    constexpr int EPI_B = BM * BN * 4;
    constexpr int SMEM_B = STAGE_B > EPI_B ? STAGE_B : EPI_B;
    __shared__ __align__(16) char smem[SMEM_B];
    ushort_t* As = (ushort_t*)smem;
    ushort_t* Bs = (ushort_t*)(smem + 2 * AHALF * 2);

    const int tid = threadIdx.x;
    const int wave = tid >> 6, lane = tid & 63;
    int bx = blockIdx.x, by = blockIdx.y;
    if (SWZ) {
        int nwg = gridDim.x * gridDim.y;
        int lin = by * gridDim.x + bx;
        int q = nwg >> 3, r = nwg & 7;
        int xcd = lin & 7, idx = lin >> 3;
        int nl = (xcd < r) ? (xcd * (q + 1) + idx)
                           : (r * (q + 1) + (xcd - r) * q + idx);
        bx = nl % gridDim.x;
        by = nl / gridDim.x;
    }
    const int m0 = bx * BM, n0 = by * BN;
    const int wr = wave / WGN, wc = wave % WGN;
    const int lr = lane & 15;
    const int q4 = lane >> 4;

    f32x4 acc[WMF][WNF] = {};

    auto stage = [&](int buf, int t) {
        const int k0g = t * BK;
        const ushort_t* Abase = (A2 != nullptr && k0g >= K1) ? A2 : A;
        const int kof = (A2 != nullptr && k0g >= K1) ? k0g - K1 : k0g;
        ushort_t* Ad = As + buf * AHALF;
        #pragma unroll
        for (int it = 0; it < (BM * BK / 8) / 256; ++it) {
            int cbase = it * 256 + wave * 64;
            int c = cbase + lane;
            int r = c & (BM - 1), c8 = c / BM;
            const ushort_t* gp = Abase + (size_t)(m0 + r) * strideA + kof + c8 * 8;
            __builtin_amdgcn_global_load_lds((const AS1 uint_t*)gp,
                                             (AS3 uint_t*)(Ad + cbase * 8), 16, 0, 0);
        }
        ushort_t* Bd = Bs + buf * BHALF;
        #pragma unroll
        for (int it = 0; it < (BN * BK / 8) / 256; ++it) {
            int cbase = it * 256 + wave * 64;
            int c = cbase + lane;
            int r = c & (BN - 1), c8 = c / BN;
            const ushort_t* gp = W + (size_t)(n0 + r) * K + k0g + c8 * 8;
            __builtin_amdgcn_global_load_lds((const AS1 uint_t*)gp,
                                             (AS3 uint_t*)(Bd + cbase * 8), 16, 0, 0);
        }
    };

    const int nsteps = K / BK;
    stage(0, 0);
    __syncthreads();
    for (int t = 0; t < nsteps; ++t) {
        const int cur = t & 1;
        if (t + 1 < nsteps) stage(cur ^ 1, t + 1);
        const ushort_t* Ab = As + cur * AHALF;
        const ushort_t* Bb = Bs + cur * BHALF;
        bf16x8 af[WMF][KK], bfr[WNF][KK];
        #pragma unroll
        for (int mi = 0; mi < WMF; ++mi)
            #pragma unroll
            for (int kk = 0; kk < KK; ++kk)
                af[mi][kk] = *reinterpret_cast<const bf16x8*>(
                    &Ab[((kk * 4 + q4) * BM + wr * (BM / WGM) + mi * 16 + lr) * 8]);
        #pragma unroll
        for (int ni = 0; ni < WNF; ++ni)
            #pragma unroll
            for (int kk = 0; kk < KK; ++kk)
                bfr[ni][kk] = *reinterpret_cast<const bf16x8*>(
                    &Bb[((kk * 4 + q4) * BN + wc * (BN / WGN) + ni * 16 + lr) * 8]);
        #pragma unroll
        for (int kk = 0; kk < KK; ++kk)
            #pragma unroll
            for (int mi = 0; mi < WMF; ++mi)
                #pragma unroll
                for (int ni = 0; ni < WNF; ++ni)
                    acc[mi][ni] = __builtin_amdgcn_mfma_f32_16x16x32_bf16(
                        af[mi][kk], bfr[ni][kk], acc[mi][ni], 0, 0, 0);
        __syncthreads();
    }

    float* tile = (float*)smem;
    #pragma unroll
    for (int mi = 0; mi < WMF; ++mi)
        #pragma unroll
        for (int ni = 0; ni < WNF; ++ni) {
            int col = wc * (BN / WGN) + ni * 16 + lr;
            float bv = bias[n0 + col];
            #pragma unroll
            for (int j = 0; j < 4; ++j) {
                int r2 = wr * (BM / WGM) + mi * 16 + q4 * 4 + j;
                tile[r2 * BN + col] = acc[mi][ni][j] + bv;
            }
        }
    __syncthreads();
    constexpr int EV = (BM * BN / 4) / 256;
    #pragma unroll
    for (int e = 0; e < EV; ++e) {
        int idx = e * 256 + tid;
        int r = idx / (BN / 4), c4 = idx % (BN / 4);
        f32x4 v = reinterpret_cast<const f32x4*>(tile)[idx];
        f32x4* dst = reinterpret_cast<f32x4*>(&C[(size_t)(m0 + r) * N + n0 + c4 * 4]);
        if (NTS) __builtin_nontemporal_store(v, dst);
        else *dst = v;
        if (WB16) {
            ushort4 ob = {f2bf(v[0]), f2bf(v[1]), f2bf(v[2]), f2bf(v[3])};
            *reinterpret_cast<ushort4*>(&Cb[(size_t)(m0 + r) * N + n0 + c4 * 4]) = ob;
        }
    }
}

// ---------------------------------------------------------------------------
// apply pass-0 update (elementwise; gate from dctx col 320).
__global__ __launch_bounds__(256) void k_apply(
    const float* __restrict__ dctx, float* __restrict__ mu,
    ushort_t* __restrict__ mub16, uint_t* __restrict__ muivP,
    float* __restrict__ alpha, float* __restrict__ feat,
    ushort_t* __restrict__ featb16, ushort_t* __restrict__ fTg) {
    int row = blockIdx.x, t = threadIdx.x;
    int l = row & (L_ - 1);
    const float* dr = dctx + (size_t)row * 352;
    if (t == 0) alpha[row] *= sigmoidf_(dr[320]);
    if (t < DS_) {
        float m = mu[(size_t)row * DS_ + t] + dr[t];
        mu[(size_t)row * DS_ + t] = m;
        mub16[(size_t)row * DS_ + t] = f2bf(m);
        uint_t v = muivP[(size_t)t * BL_ + row];
        muivP[(size_t)t * BL_ + row] = (v & 0xFFFF0000u) | (uint_t)f2bf(m);
    }
    float fn = feat[(size_t)row * DF_ + t] + dr[64 + t];
    feat[(size_t)row * DF_ + t] = fn;
    featb16[(size_t)row * DF_ + t] = f2bf(fn);
    int jb = (l >> 3) & 7, jr = l & 7;
    int jp = (l & ~63) | ((jb ^ (t & 7)) << 3) | jr;
    fTg[((size_t)((row >> 10) * DF_ + t) << 10) + jp] = f2bf(fn);
}

// gate + fuse + layernorm -> bf16 h.  grid BL_
__global__ __launch_bounds__(256) void k_fused_ln(
    const float* __restrict__ meaning, const float* __restrict__ blobm,
    const float* __restrict__ tres, const float* __restrict__ bgw,
    const float* __restrict__ bgb, const float* __restrict__ ln_g,
    const float* __restrict__ ln_b, ushort_t* __restrict__ houtb) {
    __shared__ float red[256];
    int row = blockIdx.x, t = threadIdx.x;
    int b = row >> 10;
    float m = meaning[(size_t)row * DF_ + t];
    float be = blobm[b * DF_ + t];
    float tr = tres[b];
    float gsum = block_reduce_sum(be * bgw[t] + m * bgw[256 + t], red);
    float gate = sigmoidf_(gsum + bgb[0]);
    float f = (1.f - tr) * gate * be + tr * m;
    float mean = block_reduce_sum(f, red) * (1.f / DF_);
    float d = f - mean;
    float var = block_reduce_sum(d * d, red) * (1.f / DF_);
    houtb[(size_t)row * DF_ + t] = f2bf(d * rsqrtf(var + EPS_) * ln_g[t] + ln_b[t]);
}

extern "C" void kernel_launch(void* const* d_in, const int* in_sizes, int n_in,
                              void* d_out, int out_size, void* d_ws, size_t ws_size,
                              hipStream_t stream) {
    const int*   tok      = (const int*)d_in[0];
    const float* tok_mu   = (const float*)d_in[1];
    const float* tok_lv   = (const float*)d_in[2];
    const float* tok_ra   = (const float*)d_in[3];
    const float* tok_f    = (const float*)d_in[4];
    const float* pos_mu   = (const float*)d_in[5];
    const float* qproj_w  = (const float*)d_in[6];
    const float* qproj_b  = (const float*)d_in[7];
    const float* hproj_w  = (const float*)d_in[8];
    const float* hproj_b  = (const float*)d_in[9];
    const float* mu_up_w  = (const float*)d_in[10];
    const float* mu_up_b  = (const float*)d_in[11];
    const float* agate_w  = (const float*)d_in[12];
    const float* agate_b  = (const float*)d_in[13];
    const float* ffn_w    = (const float*)d_in[14];
    const float* ffn_b    = (const float*)d_in[15];
    const float* ln_g     = (const float*)d_in[16];
    const float* ln_b     = (const float*)d_in[17];
    const float* lm_w     = (const float*)d_in[18];
    const float* lm_b     = (const float*)d_in[19];
    const float* blob_mu  = (const float*)d_in[20];
    const float* blob_lv  = (const float*)d_in[21];
    const float* blob_ra  = (const float*)d_in[22];
    const float* blob_f   = (const float*)d_in[23];
    const float* bgate_w  = (const float*)d_in[24];
    const float* bgate_b  = (const float*)d_in[25];
    float* out = (float*)d_out;

    float* ws = (float*)d_ws;
    float* mu      = ws;                        // BL*64
    float* alpha   = mu + BL_ * DS_;            // BL
    float* feat    = alpha + BL_;               // BL*256
    float* blobm   = feat + BL_ * DF_;          // B*256
    float* tres    = blobm + B_ * DF_;          // pad 64
    float* q       = tres + 64;                 // BL*512
    float* meaning = q + BL_ * 512;             // BL*256
    float* dctx    = meaning + BL_ * DF_;       // BL*352
    float* cbias   = dctx + (size_t)BL_ * 352;  // 352 (pad 384)
    uint_t* muivP  = (uint_t*)(cbias + 384);              // 64*BL
    ushort_t* fTg   = (ushort_t*)(muivP + (size_t)DS_ * BL_); // B*256*1024
    ushort_t* mub16 = fTg + (size_t)B_ * DF_ * L_;        // BL*64
    ushort_t* featb16 = mub16 + (size_t)BL_ * DS_;        // BL*256
    ushort_t* meanb16 = featb16 + (size_t)BL_ * DF_;      // BL*256
    ushort_t* mcatb = meanb16 + (size_t)BL_ * DF_;        // BL*2048
    ushort_t* hbufb = mcatb + (size_t)BL_ * 2048;         // BL*256
    ushort_t* wbf   = hbufb + (size_t)BL_ * DF_;          // V*256
    ushort_t* hpwbf = wbf + (size_t)V_ * DF_;             // 256*2048
    ushort_t* qpwbf = hpwbf + (size_t)DF_ * 2048;         // 512*64
    ushort_t* cwbf  = qpwbf + (size_t)512 * 64;           // 352*512

    k_setup<<<NST_ + 1, 256, 0, stream>>>(
        tok, tok_mu, tok_lv, tok_ra, tok_f, pos_mu,
        qproj_w, mu_up_w, mu_up_b, ffn_w, ffn_b, agate_w, agate_b,
        hproj_w, lm_w, blob_mu, blob_lv, blob_ra, blob_f,
        qpwbf, cwbf, hpwbf, wbf, cbias,
        mu, mub16, muivP, alpha, feat, featb16, fTg, blobm, tres);

    for (int p = 0; p < 2; ++p) {
        gemm_mfma2<32, 32, 64, 2, 2, false, false, false>
            <<<dim3(BL_ / 32, 512 / 32), 256, 0, stream>>>(
            mub16, nullptr, 0, DS_, qpwbf, qproj_b, q, nullptr, BL_, 512, DS_);
        k_attn7<<<B_ * L_ / 2, 512, 0, stream>>>(q, muivP, alpha, fTg, mcatb);
        if (p == 0) {
            gemm_mfma2<32, 32, 128, 2, 2, false, true, false>
                <<<dim3(BL_ / 32, DF_ / 32), 256, 0, stream>>>(
                mcatb, nullptr, 0, H_ * DF_, hpwbf, hproj_b, meaning, meanb16,
                BL_, DF_, H_ * DF_);
            gemm_mfma2<32, 32, 128, 2, 2, false, false, false>
                <<<dim3(BL_ / 32, 352 / 32), 256, 0, stream>>>(
                featb16, meanb16, DF_, DF_, cwbf, cbias, dctx, nullptr,
                BL_, 352, 512);
            k_apply<<<BL_, 256, 0, stream>>>(dctx, mu, mub16, muivP, alpha,
                                             feat, featb16, fTg);
        } else {
            gemm_mfma2<32, 32, 128, 2, 2, false, false, false>
                <<<dim3(BL_ / 32, DF_ / 32), 256, 0, stream>>>(
                mcatb, nullptr, 0, H_ * DF_, hpwbf, hproj_b, meaning, nullptr,
                BL_, DF_, H_ * DF_);
        }
    }

    k_fused_ln<<<BL_, 256, 0, stream>>>(meaning, blobm, tres, bgate_w, bgate_b,
                                        ln_g, ln_b, hbufb);
    gemm_mfma2<128, 128, 64, 2, 2, true, false, true>
        <<<dim3(BL_ / 128, V_ / 128), 256, 0, stream>>>(
        hbufb, nullptr, 0, DF_, wbf, lm_b, out, nullptr, BL_, V_, DF_);
}

// Round 16
// 293.811 us; speedup vs baseline: 1.0677x; 1.0191x over previous
//
#include <hip/hip_runtime.h>
#include <hip/hip_bf16.h>
#include <cstdint>
#include <cstddef>

#define V_   32000
#define DS_  64
#define DF_  256
#define H_   8
#define L_   1024
#define B_   2
#define NB_  512
#define BL_  2048
#define EPS_ 1e-5f

typedef unsigned short ushort_t;
typedef unsigned int uint_t;
typedef short bf16x8 __attribute__((ext_vector_type(8)));
typedef float f32x4 __attribute__((ext_vector_type(4)));
#define AS1 __attribute__((address_space(1)))
#define AS3 __attribute__((address_space(3)))

__device__ __forceinline__ float sigmoidf_(float x) { return 1.f / (1.f + __expf(-x)); }
__device__ __forceinline__ ushort_t f2bf(float x) {
    __hip_bfloat16 b = __float2bfloat16(x);
    return __builtin_bit_cast(ushort_t, b);
}
__device__ __forceinline__ uint_t packbf(float lo, float hi) {
    return ((uint_t)f2bf(hi) << 16) | (uint_t)f2bf(lo);
}
__device__ __forceinline__ float bflo(uint_t v) {
    return __builtin_bit_cast(float, v << 16);
}
__device__ __forceinline__ float bfhi(uint_t v) {
    return __builtin_bit_cast(float, v & 0xFFFF0000u);
}

__device__ __forceinline__ float block_reduce_sum(float v, float* red) {
    int t = threadIdx.x;
    red[t] = v;
    __syncthreads();
    for (int s = 128; s > 0; s >>= 1) {
        if (t < s) red[t] += red[t + s];
        __syncthreads();
    }
    float r = red[0];
    __syncthreads();
    return r;
}

// ---------------------------------------------------------------------------
// Merged setup: weight cvt (batched 4096 floats/block) | gather | query+blob
// | combined bias.
#define NCVT_ 2180
#define NGA_  (NCVT_ + BL_)
#define NST_  (NGA_ + B_)
__global__ __launch_bounds__(256) void k_setup(
    const int* __restrict__ tok, const float* __restrict__ tok_mu,
    const float* __restrict__ tok_lv, const float* __restrict__ tok_ra,
    const float* __restrict__ tok_f, const float* __restrict__ pos_mu,
    const float* __restrict__ qproj_w, const float* __restrict__ mu_up_w,
    const float* __restrict__ mu_up_b, const float* __restrict__ ffn_w,
    const float* __restrict__ ffn_b, const float* __restrict__ agate_w,
    const float* __restrict__ agate_b, const float* __restrict__ hproj_w,
    const float* __restrict__ lm_w, const float* __restrict__ blob_mu,
    const float* __restrict__ blob_lv, const float* __restrict__ blob_ra,
    const float* __restrict__ blob_f,
    ushort_t* __restrict__ qpwbf, ushort_t* __restrict__ cwbf,
    ushort_t* __restrict__ hpwbf, ushort_t* __restrict__ wbf,
    float* __restrict__ cbias,
    float* __restrict__ mu, ushort_t* __restrict__ mub16,
    uint_t* __restrict__ muivP, float* __restrict__ alpha,
    float* __restrict__ feat, ushort_t* __restrict__ featb16,
    ushort_t* __restrict__ fTg, float* __restrict__ blobm,
    float* __restrict__ tres) {
    int blk = blockIdx.x;
    int t = threadIdx.x;
    if (blk < NCVT_) {
        const float* s = nullptr; ushort_t* dd; int base; bool cw = false;
        if (blk < 8)        { s = qproj_w; dd = qpwbf; base = blk; }
        else if (blk < 52)  { dd = cwbf; base = blk - 8; cw = true; }
        else if (blk < 180) { s = hproj_w; dd = hpwbf; base = blk - 52; }
        else                { s = lm_w; dd = wbf; base = blk - 180; }
        #pragma unroll
        for (int k = 0; k < 4; ++k) {
            int i = base * 4096 + k * 1024 + t * 4;
            float4 v = {0.f, 0.f, 0.f, 0.f};
            if (cw) {
                int r = i >> 9, c = i & 511;
                if (r < 64)        v = *reinterpret_cast<const float4*>(mu_up_w + r * 512 + c);
                else if (r < 320)  v = *reinterpret_cast<const float4*>(ffn_w + (r - 64) * 512 + c);
                else if (r == 320) v = *reinterpret_cast<const float4*>(agate_w + c);
            } else {
                v = *reinterpret_cast<const float4*>(s + i);
            }
            ushort4 o = {f2bf(v.x), f2bf(v.y), f2bf(v.z), f2bf(v.w)};
            *reinterpret_cast<ushort4*>(dd + i) = o;
        }
        return;
    }
    if (blk < NGA_) {        // gather
        int row = blk - NCVT_;
        int l = row & (L_ - 1);
        int v = tok[row];
        if (t < DS_) {
            float m = tok_mu[(size_t)v * DS_ + t] + pos_mu[l * DS_ + t];
            mu[(size_t)row * DS_ + t] = m;
            mub16[(size_t)row * DS_ + t] = f2bf(m);
            float ivv = __expf(-tok_lv[(size_t)v * DS_ + t]);
            muivP[(size_t)t * BL_ + row] = packbf(m, ivv);
        }
        float fv = tok_f[(size_t)v * DF_ + t];
        feat[(size_t)row * DF_ + t] = fv;
        featb16[(size_t)row * DF_ + t] = f2bf(fv);
        int jb = (l >> 3) & 7, jr = l & 7;
        int jp = (l & ~63) | ((jb ^ (t & 7)) << 3) | jr;
        fTg[((size_t)((row >> 10) * DF_ + t) << 10) + jp] = f2bf(fv);
        if (t == 0) alpha[row] = sigmoidf_(tok_ra[v]);
        return;
    }
    if (blk < NST_) {        // query + blob
        __shared__ float red[256];
        __shared__ int stok[L_];
        __shared__ float sq[DS_];
        __shared__ float sa[NB_];
        __shared__ float sp[NB_];
        int b = blk - NGA_;
        for (int l = t; l < L_; l += 256) stok[l] = tok[b * L_ + l];
        __syncthreads();
        int d = t & 63, c = t >> 6;
        float s = 0.f;
        for (int l = c; l < L_; l += 4)
            s += tok_mu[(size_t)stok[l] * DS_ + d] + pos_mu[l * DS_ + d];
        red[t] = s;
        __syncthreads();
        if (c == 0)
            sq[d] = (red[d] + red[64 + d] + red[128 + d] + red[192 + d]) * (1.f / L_);
        __syncthreads();
        for (int n = t; n < NB_; n += 256) {
            float d2 = 0.f;
            for (int dd = 0; dd < DS_; ++dd) {
                float diff = sq[dd] - blob_mu[n * DS_ + dd];
                d2 += __expf(-blob_lv[n * DS_ + dd]) * diff * diff;
            }
            float a = sigmoidf_(blob_ra[n]) * __expf(-0.5f * d2);
            sa[n] = a;
            sp[n] = 1.f - a;
        }
        __syncthreads();
        int n0 = t, n1 = t + 256;
        for (int s2 = 1; s2 < NB_; s2 <<= 1) {
            float t0 = (n0 >= s2) ? sp[n0 - s2] : 1.f;
            float t1 = (n1 >= s2) ? sp[n1 - s2] : 1.f;
            __syncthreads();
            sp[n0] *= t0;
            sp[n1] *= t1;
            __syncthreads();
        }
        float w0 = sa[n0] * (n0 ? sp[n0 - 1] : 1.f);
        float w1 = sa[n1] * sp[n1 - 1];
        __syncthreads();
        sa[n0] = w0;
        sa[n1] = w1;
        if (t == 0) tres[b] = sp[NB_ - 1];
        __syncthreads();
        float acc = 0.f;
        for (int n = 0; n < NB_; ++n) acc += sa[n] * blob_f[n * DF_ + t];
        blobm[b * DF_ + t] = acc;
        return;
    }
    // combined bias (352)
    for (int idx = t; idx < 352; idx += 256) {
        float bv = 0.f;
        if (idx < 64) bv = mu_up_b[idx];
        else if (idx < 320) bv = ffn_b[idx - 64];
        else if (idx == 320) bv = agate_b[0];
        cbias[idx] = bv;
    }
}

// ---------------------------------------------------------------------------
// Attention v7: TWO rows (i0, i0+1) per 512-thread block (r11/r12, verified).
__global__ __launch_bounds__(512) void k_attn7(
    const float* __restrict__ q, const uint_t* __restrict__ muivP,
    const float* __restrict__ alpha, const ushort_t* __restrict__ fTg,
    ushort_t* __restrict__ mcatb) {
    __shared__ __align__(16) uint_t smiu[64 * 64];      // [d][jl]  16 KB
    __shared__ __align__(16) ushort_t sfT[256 * 64];    // [c][j']  32 KB
    __shared__ __align__(16) ushort_t sw16[16][72];     // A-tile (16 live rows)
    __shared__ float sqA[512], sqB[512];
    __shared__ float sT[16];
    int tid = threadIdx.x;
    int w = tid >> 6, lane = tid & 63;
    int bid = blockIdx.x;
    int b = bid >> 9;
    int i0 = (bid & 511) * 2, i1 = i0 + 1;
    int row0 = b * L_ + i0;
    const int lr = lane & 15, q4 = lane >> 4;

    sqA[tid] = q[(size_t)row0 * 512 + tid];
    sqB[tid] = q[(size_t)(row0 + 1) * 512 + tid];

    float T0 = 1.f, T1 = 1.f;
    f32x4 acc0 = {}, acc1 = {};

    for (int j0 = 0; j0 <= i1; j0 += 64) {
        __syncthreads();   // publish sq/sT; protect prev-chunk LDS
        if (j0 > 0) {
            bool alive = false;
            #pragma unroll
            for (int h = 0; h < 16; ++h) alive |= (sT[h] >= 1e-12f);
            if (!alive) break;
        }
        // stage muiv chunk (wave w covers d rows w*8..w*8+7)
        {
            const uint_t* src = muivP + b * L_ + j0;
            #pragma unroll
            for (int r = 0; r < 2; ++r) {
                int d = w * 8 + r * 4 + q4;
                const uint_t* gp = src + (size_t)d * BL_ + lr * 4;
                __builtin_amdgcn_global_load_lds((const AS1 uint_t*)gp,
                    (AS3 uint_t*)&smiu[(w * 8 + r * 4) * 64], 16, 0, 0);
            }
        }
        // stage feature chunk K-major: wave w covers c rows w*32..w*32+31
        {
            #pragma unroll
            for (int it = 0; it < 4; ++it) {
                int c0 = w * 32 + it * 8;
                const ushort_t* gp = fTg +
                    ((size_t)(b * DF_ + c0 + (lane >> 3)) << 10) + j0 + (lane & 7) * 8;
                __builtin_amdgcn_global_load_lds((const AS1 uint_t*)gp,
                    (AS3 uint_t*)&sfT[c0 * 64], 16, 0, 0);
            }
        }
        __syncthreads();   // stage landed

        // phase A: d2 for both rows (shared LDS read)
        int jj = j0 + lane;
        int jc = jj <= i1 ? jj : i1;
        float alv = alpha[b * L_ + jc];
        float d20 = 0.f, d21 = 0.f;
        #pragma unroll 8
        for (int d = 0; d < 64; ++d) {
            uint_t v = smiu[d * 64 + lane];
            float m = bflo(v), iv = bfhi(v);
            float f0 = sqA[w * 64 + d] - m;
            float f1 = sqB[w * 64 + d] - m;
            d20 = fmaf(iv * f0, f0, d20);
            d21 = fmaf(iv * f1, f1, d21);
        }
        float a0 = (jj <= i0) ? alv * __expf(-0.5f * d20) : 0.f;
        float a1 = (jj <= i1) ? alv * __expf(-0.5f * d21) : 0.f;

        // phase B: two wave product-scans
        float p = 1.f - a0;
        #pragma unroll
        for (int s = 1; s < 64; s <<= 1) {
            float tt = __shfl_up(p, s, 64);
            if (lane >= s) p *= tt;
        }
        float Tex = __shfl_up(p, 1, 64);
        if (lane == 0) Tex = 1.f;
        sw16[w][lane] = f2bf(a0 * T0 * Tex);
        T0 *= __shfl(p, 63, 64);

        p = 1.f - a1;
        #pragma unroll
        for (int s = 1; s < 64; s <<= 1) {
            float tt = __shfl_up(p, s, 64);
            if (lane >= s) p *= tt;
        }
        Tex = __shfl_up(p, 1, 64);
        if (lane == 0) Tex = 1.f;
        sw16[w + 8][lane] = f2bf(a1 * T1 * Tex);
        T1 *= __shfl(p, 63, 64);

        if (lane == 0) { sT[w] = T0; sT[w + 8] = T1; }
        __syncthreads();   // sw16 complete

        // phase C: PV via MFMA (wave w owns col tiles 2w, 2w+1; A fully live)
        #pragma unroll
        for (int kk = 0; kk < 2; ++kk) {
            bf16x8 afr = *reinterpret_cast<const bf16x8*>(
                (const char*)sw16 + lr * 144 + kk * 64 + q4 * 16);
            {
                int c = (w * 2 + 0) * 16 + lr;
                int bo = c * 128 + ((kk * 64 + q4 * 16) ^ ((c & 7) << 4));
                bf16x8 bfr = *reinterpret_cast<const bf16x8*>((const char*)sfT + bo);
                acc0 = __builtin_amdgcn_mfma_f32_16x16x32_bf16(afr, bfr, acc0, 0, 0, 0);
            }
            {
                int c = (w * 2 + 1) * 16 + lr;
                int bo = c * 128 + ((kk * 64 + q4 * 16) ^ ((c & 7) << 4));
                bf16x8 bfr = *reinterpret_cast<const bf16x8*>((const char*)sfT + bo);
                acc1 = __builtin_amdgcn_mfma_f32_16x16x32_bf16(afr, bfr, acc1, 0, 0, 0);
            }
        }
    }
    // epilogue: C row r -> head r&7, row-parity r>>3
    #pragma unroll
    for (int j = 0; j < 4; ++j) {
        int r = q4 * 4 + j;
        int h = r & 7, par = r >> 3;
        size_t rw = (size_t)(row0 + par) * 2048 + h * 256;
        mcatb[rw + (w * 2 + 0) * 16 + lr] = f2bf(acc0[j]);
        mcatb[rw + (w * 2 + 1) * 16 + lr] = f2bf(acc1[j]);
    }
}

// ---------------------------------------------------------------------------
// bf16 MFMA GEMM with optional XCD swizzle (SWZ) and optional fused APPLY
// epilogue (performs k_apply's per-element updates in place of writing C;
// regions are column-local: [0,64)->mu, [64,320)->feat, col 320 -> alpha).
template <int BM, int BN, int BK, int WGM, int WGN, bool NTS, bool WB16,
          bool SWZ, bool APPLY>
__global__ __launch_bounds__(256) void gemm_mfma2(
    const ushort_t* __restrict__ A, const ushort_t* __restrict__ A2, int K1,
    int strideA, const ushort_t* __restrict__ W, const float* __restrict__ bias,
    float* __restrict__ C, ushort_t* __restrict__ Cb, int M, int N, int K,
    float* __restrict__ muP, ushort_t* __restrict__ mub16P,
    uint_t* __restrict__ muivPP, float* __restrict__ alphaP,
    float* __restrict__ featP, ushort_t* __restrict__ featb16P,
    ushort_t* __restrict__ fTgP) {
    constexpr int WMF = BM / WGM / 16;
    constexpr int WNF = BN / WGN / 16;
    constexpr int KK  = BK / 32;
    constexpr int AHALF = BM * BK;
    constexpr int BHALF = BN * BK;
    constexpr int STAGE_B = 2 * (AHALF + BHALF) * 2;
    constexpr int EPI_B = BM * BN * 4;
    constexpr int SMEM_B = STAGE_B > EPI_B ? STAGE_B : EPI_B;
    __shared__ __align__(16) char smem[SMEM_B];
    ushort_t* As = (ushort_t*)smem;
    ushort_t* Bs = (ushort_t*)(smem + 2 * AHALF * 2);

    const int tid = threadIdx.x;
    const int wave = tid >> 6, lane = tid & 63;
    int bx = blockIdx.x, by = blockIdx.y;
    if (SWZ) {
        int nwg = gridDim.x * gridDim.y;
        int lin = by * gridDim.x + bx;
        int q = nwg >> 3, r = nwg & 7;
        int xcd = lin & 7, idx = lin >> 3;
        int nl = (xcd < r) ? (xcd * (q + 1) + idx)
                           : (r * (q + 1) + (xcd - r) * q + idx);
        bx = nl % gridDim.x;
        by = nl / gridDim.x;
    }
    const int m0 = bx * BM, n0 = by * BN;
    const int wr = wave / WGN, wc = wave % WGN;
    const int lr = lane & 15;
    const int q4 = lane >> 4;

    f32x4 acc[WMF][WNF] = {};

    auto stage = [&](int buf, int t) {
        const int k0g = t * BK;
        const ushort_t* Abase = (A2 != nullptr && k0g >= K1) ? A2 : A;
        const int kof = (A2 != nullptr && k0g >= K1) ? k0g - K1 : k0g;
        ushort_t* Ad = As + buf * AHALF;
        #pragma unroll
        for (int it = 0; it < (BM * BK / 8) / 256; ++it) {
            int cbase = it * 256 + wave * 64;
            int c = cbase + lane;
            int r = c & (BM - 1), c8 = c / BM;
            const ushort_t* gp = Abase + (size_t)(m0 + r) * strideA + kof + c8 * 8;
            __builtin_amdgcn_global_load_lds((const AS1 uint_t*)gp,
                                             (AS3 uint_t*)(Ad + cbase * 8), 16, 0, 0);
        }
        ushort_t* Bd = Bs + buf * BHALF;
        #pragma unroll
        for (int it = 0; it < (BN * BK / 8) / 256; ++it) {
            int cbase = it * 256 + wave * 64;
            int c = cbase + lane;
            int r = c & (BN - 1), c8 = c / BN;
            const ushort_t* gp = W + (size_t)(n0 + r) * K + k0g + c8 * 8;
            __builtin_amdgcn_global_load_lds((const AS1 uint_t*)gp,
                                             (AS3 uint_t*)(Bd + cbase * 8), 16, 0, 0);
        }
    };

    const int nsteps = K / BK;
    stage(0, 0);
    __syncthreads();
    for (int t = 0; t < nsteps; ++t) {
        const int cur = t & 1;
        if (t + 1 < nsteps) stage(cur ^ 1, t + 1);
        const ushort_t* Ab = As + cur * AHALF;
        const ushort_t* Bb = Bs + cur * BHALF;
        bf16x8 af[WMF][KK], bfr[WNF][KK];
        #pragma unroll
        for (int mi = 0; mi < WMF; ++mi)
            #pragma unroll
            for (int kk = 0; kk < KK; ++kk)
                af[mi][kk] = *reinterpret_cast<const bf16x8*>(
                    &Ab[((kk * 4 + q4) * BM + wr * (BM / WGM) + mi * 16 + lr) * 8]);
        #pragma unroll
        for (int ni = 0; ni < WNF; ++ni)
            #pragma unroll
            for (int kk = 0; kk < KK; ++kk)
                bfr[ni][kk] = *reinterpret_cast<const bf16x8*>(
                    &Bb[((kk * 4 + q4) * BN + wc * (BN / WGN) + ni * 16 + lr) * 8]);
        #pragma unroll
        for (int kk = 0; kk < KK; ++kk)
            #pragma unroll
            for (int mi = 0; mi < WMF; ++mi)
                #pragma unroll
                for (int ni = 0; ni < WNF; ++ni)
                    acc[mi][ni] = __builtin_amdgcn_mfma_f32_16x16x32_bf16(
                        af[mi][kk], bfr[ni][kk], acc[mi][ni], 0, 0, 0);
        __syncthreads();
    }

    float* tile = (float*)smem;
    #pragma unroll
    for (int mi = 0; mi < WMF; ++mi)
        #pragma unroll
        for (int ni = 0; ni < WNF; ++ni) {
            int col = wc * (BN / WGN) + ni * 16 + lr;
            float bv = bias[n0 + col];
            #pragma unroll
            for (int j = 0; j < 4; ++j) {
                int r2 = wr * (BM / WGM) + mi * 16 + q4 * 4 + j;
                tile[r2 * BN + col] = acc[mi][ni][j] + bv;
            }
        }
    __syncthreads();
    constexpr int EV = (BM * BN / 4) / 256;
    #pragma unroll
    for (int e = 0; e < EV; ++e) {
        int idx = e * 256 + tid;
        int r = idx / (BN / 4), c4 = idx % (BN / 4);
        f32x4 v = reinterpret_cast<const f32x4*>(tile)[idx];
        if (APPLY) {
            int row = m0 + r;
            int col0 = n0 + c4 * 4;
            if (col0 < 64) {               // dmu region
                #pragma unroll
                for (int k = 0; k < 4; ++k) {
                    int d = col0 + k;
                    float m = muP[(size_t)row * DS_ + d] + v[k];
                    muP[(size_t)row * DS_ + d] = m;
                    mub16P[(size_t)row * DS_ + d] = f2bf(m);
                    size_t ix = (size_t)d * BL_ + row;
                    uint_t old = muivPP[ix];
                    muivPP[ix] = (old & 0xFFFF0000u) | (uint_t)f2bf(m);
                }
            } else if (col0 < 320) {       // dffn region
                int l = row & (L_ - 1);
                int bb = row >> 10;
                int jb = (l >> 3) & 7, jr = l & 7;
                #pragma unroll
                for (int k = 0; k < 4; ++k) {
                    int fc = col0 + k - 64;
                    float fn = featP[(size_t)row * DF_ + fc] + v[k];
                    featP[(size_t)row * DF_ + fc] = fn;
                    featb16P[(size_t)row * DF_ + fc] = f2bf(fn);
                    int jp = (l & ~63) | ((jb ^ (fc & 7)) << 3) | jr;
                    fTgP[((size_t)(bb * DF_ + fc) << 10) + jp] = f2bf(fn);
                }
            } else {                       // gate region (col 320 only)
                #pragma unroll
                for (int k = 0; k < 4; ++k)
                    if (col0 + k == 320) alphaP[row] *= sigmoidf_(v[k]);
            }
        } else {
            f32x4* dst = reinterpret_cast<f32x4*>(&C[(size_t)(m0 + r) * N + n0 + c4 * 4]);
            if (NTS) __builtin_nontemporal_store(v, dst);
            else *dst = v;
            if (WB16) {
                ushort4 ob = {f2bf(v[0]), f2bf(v[1]), f2bf(v[2]), f2bf(v[3])};
                *reinterpret_cast<ushort4*>(&Cb[(size_t)(m0 + r) * N + n0 + c4 * 4]) = ob;
            }
        }
    }
}

// gate + fuse + layernorm -> bf16 h.  grid BL_
__global__ __launch_bounds__(256) void k_fused_ln(
    const float* __restrict__ meaning, const float* __restrict__ blobm,
    const float* __restrict__ tres, const float* __restrict__ bgw,
    const float* __restrict__ bgb, const float* __restrict__ ln_g,
    const float* __restrict__ ln_b, ushort_t* __restrict__ houtb) {
    __shared__ float red[256];
    int row = blockIdx.x, t = threadIdx.x;
    int b = row >> 10;
    float m = meaning[(size_t)row * DF_ + t];
    float be = blobm[b * DF_ + t];
    float tr = tres[b];
    float gsum = block_reduce_sum(be * bgw[t] + m * bgw[256 + t], red);
    float gate = sigmoidf_(gsum + bgb[0]);
    float f = (1.f - tr) * gate * be + tr * m;
    float mean = block_reduce_sum(f, red) * (1.f / DF_);
    float d = f - mean;
    float var = block_reduce_sum(d * d, red) * (1.f / DF_);
    houtb[(size_t)row * DF_ + t] = f2bf(d * rsqrtf(var + EPS_) * ln_g[t] + ln_b[t]);
}

extern "C" void kernel_launch(void* const* d_in, const int* in_sizes, int n_in,
                              void* d_out, int out_size, void* d_ws, size_t ws_size,
                              hipStream_t stream) {
    const int*   tok      = (const int*)d_in[0];
    const float* tok_mu   = (const float*)d_in[1];
    const float* tok_lv   = (const float*)d_in[2];
    const float* tok_ra   = (const float*)d_in[3];
    const float* tok_f    = (const float*)d_in[4];
    const float* pos_mu   = (const float*)d_in[5];
    const float* qproj_w  = (const float*)d_in[6];
    const float* qproj_b  = (const float*)d_in[7];
    const float* hproj_w  = (const float*)d_in[8];
    const float* hproj_b  = (const float*)d_in[9];
    const float* mu_up_w  = (const float*)d_in[10];
    const float* mu_up_b  = (const float*)d_in[11];
    const float* agate_w  = (const float*)d_in[12];
    const float* agate_b  = (const float*)d_in[13];
    const float* ffn_w    = (const float*)d_in[14];
    const float* ffn_b    = (const float*)d_in[15];
    const float* ln_g     = (const float*)d_in[16];
    const float* ln_b     = (const float*)d_in[17];
    const float* lm_w     = (const float*)d_in[18];
    const float* lm_b     = (const float*)d_in[19];
    const float* blob_mu  = (const float*)d_in[20];
    const float* blob_lv  = (const float*)d_in[21];
    const float* blob_ra  = (const float*)d_in[22];
    const float* blob_f   = (const float*)d_in[23];
    const float* bgate_w  = (const float*)d_in[24];
    const float* bgate_b  = (const float*)d_in[25];
    float* out = (float*)d_out;

    float* ws = (float*)d_ws;
    float* mu      = ws;                        // BL*64
    float* alpha   = mu + BL_ * DS_;            // BL
    float* feat    = alpha + BL_;               // BL*256
    float* blobm   = feat + BL_ * DF_;          // B*256
    float* tres    = blobm + B_ * DF_;          // pad 64
    float* q       = tres + 64;                 // BL*512
    float* meaning = q + BL_ * 512;             // BL*256
    float* cbias   = meaning + BL_ * DF_;       // 352 (pad 384)
    uint_t* muivP  = (uint_t*)(cbias + 384);              // 64*BL
    ushort_t* fTg   = (ushort_t*)(muivP + (size_t)DS_ * BL_); // B*256*1024
    ushort_t* mub16 = fTg + (size_t)B_ * DF_ * L_;        // BL*64
    ushort_t* featb16 = mub16 + (size_t)BL_ * DS_;        // BL*256
    ushort_t* meanb16 = featb16 + (size_t)BL_ * DF_;      // BL*256
    ushort_t* mcatb = meanb16 + (size_t)BL_ * DF_;        // BL*2048
    ushort_t* hbufb = mcatb + (size_t)BL_ * 2048;         // BL*256
    ushort_t* wbf   = hbufb + (size_t)BL_ * DF_;          // V*256
    ushort_t* hpwbf = wbf + (size_t)V_ * DF_;             // 256*2048
    ushort_t* qpwbf = hpwbf + (size_t)DF_ * 2048;         // 512*64
    ushort_t* cwbf  = qpwbf + (size_t)512 * 64;           // 352*512

    k_setup<<<NST_ + 1, 256, 0, stream>>>(
        tok, tok_mu, tok_lv, tok_ra, tok_f, pos_mu,
        qproj_w, mu_up_w, mu_up_b, ffn_w, ffn_b, agate_w, agate_b,
        hproj_w, lm_w, blob_mu, blob_lv, blob_ra, blob_f,
        qpwbf, cwbf, hpwbf, wbf, cbias,
        mu, mub16, muivP, alpha, feat, featb16, fTg, blobm, tres);

    for (int p = 0; p < 2; ++p) {
        gemm_mfma2<32, 32, 64, 2, 2, false, false, false, false>
            <<<dim3(BL_ / 32, 512 / 32), 256, 0, stream>>>(
            mub16, nullptr, 0, DS_, qpwbf, qproj_b, q, nullptr, BL_, 512, DS_,
            nullptr, nullptr, nullptr, nullptr, nullptr, nullptr, nullptr);
        k_attn7<<<B_ * L_ / 2, 512, 0, stream>>>(q, muivP, alpha, fTg, mcatb);
        if (p == 0) {
            gemm_mfma2<32, 32, 128, 2, 2, false, true, false, false>
                <<<dim3(BL_ / 32, DF_ / 32), 256, 0, stream>>>(
                mcatb, nullptr, 0, H_ * DF_, hpwbf, hproj_b, meaning, meanb16,
                BL_, DF_, H_ * DF_,
                nullptr, nullptr, nullptr, nullptr, nullptr, nullptr, nullptr);
            gemm_mfma2<32, 32, 128, 2, 2, false, false, false, true>
                <<<dim3(BL_ / 32, 352 / 32), 256, 0, stream>>>(
                featb16, meanb16, DF_, DF_, cwbf, cbias, nullptr, nullptr,
                BL_, 352, 512,
                mu, mub16, muivP, alpha, feat, featb16, fTg);
        } else {
            gemm_mfma2<32, 32, 128, 2, 2, false, false, false, false>
                <<<dim3(BL_ / 32, DF_ / 32), 256, 0, stream>>>(
                mcatb, nullptr, 0, H_ * DF_, hpwbf, hproj_b, meaning, nullptr,
                BL_, DF_, H_ * DF_,
                nullptr, nullptr, nullptr, nullptr, nullptr, nullptr, nullptr);
        }
    }

    k_fused_ln<<<BL_, 256, 0, stream>>>(meaning, blobm, tres, bgate_w, bgate_b,
                                        ln_g, ln_b, hbufb);
    gemm_mfma2<128, 128, 64, 2, 2, true, false, true, false>
        <<<dim3(BL_ / 128, V_ / 128), 256, 0, stream>>>(
        hbufb, nullptr, 0, DF_, wbf, lm_b, out, nullptr, BL_, V_, DF_,
        nullptr, nullptr, nullptr, nullptr, nullptr, nullptr, nullptr);
}

// Round 17
// 286.573 us; speedup vs baseline: 1.0947x; 1.0253x over previous
//
#include <hip/hip_runtime.h>
#include <hip/hip_bf16.h>
#include <cstdint>
#include <cstddef>

#define V_   32000
#define DS_  64
#define DF_  256
#define H_   8
#define L_   1024
#define B_   2
#define NB_  512
#define BL_  2048
#define EPS_ 1e-5f

typedef unsigned short ushort_t;
typedef unsigned int uint_t;
typedef short bf16x8 __attribute__((ext_vector_type(8)));
typedef float f32x4 __attribute__((ext_vector_type(4)));
#define AS1 __attribute__((address_space(1)))
#define AS3 __attribute__((address_space(3)))

__device__ __forceinline__ float sigmoidf_(float x) { return 1.f / (1.f + __expf(-x)); }
__device__ __forceinline__ ushort_t f2bf(float x) {
    __hip_bfloat16 b = __float2bfloat16(x);
    return __builtin_bit_cast(ushort_t, b);
}
__device__ __forceinline__ uint_t packbf(float lo, float hi) {
    return ((uint_t)f2bf(hi) << 16) | (uint_t)f2bf(lo);
}
__device__ __forceinline__ float bflo(uint_t v) {
    return __builtin_bit_cast(float, v << 16);
}
__device__ __forceinline__ float bfhi(uint_t v) {
    return __builtin_bit_cast(float, v & 0xFFFF0000u);
}

__device__ __forceinline__ float block_reduce_sum(float v, float* red) {
    int t = threadIdx.x;
    red[t] = v;
    __syncthreads();
    for (int s = 128; s > 0; s >>= 1) {
        if (t < s) red[t] += red[t + s];
        __syncthreads();
    }
    float r = red[0];
    __syncthreads();
    return r;
}

// ---------------------------------------------------------------------------
// Merged setup: weight cvt | gather | query+blob | combined bias |
// pass-0 qproj GEMM tiles (self-gathered A, inline-converted B; no deps).
#define NCVT_ 2180
#define NGA_  (NCVT_ + BL_)
#define NST_  (NGA_ + B_)
#define NQP_  (NST_ + 1)                 // bias block at NST_
#define NTOT_ (NQP_ + 1024)              // 1024 qproj tiles (64 x 16)
__global__ __launch_bounds__(256) void k_setup(
    const int* __restrict__ tok, const float* __restrict__ tok_mu,
    const float* __restrict__ tok_lv, const float* __restrict__ tok_ra,
    const float* __restrict__ tok_f, const float* __restrict__ pos_mu,
    const float* __restrict__ qproj_w, const float* __restrict__ qproj_b,
    const float* __restrict__ mu_up_w, const float* __restrict__ mu_up_b,
    const float* __restrict__ ffn_w, const float* __restrict__ ffn_b,
    const float* __restrict__ agate_w, const float* __restrict__ agate_b,
    const float* __restrict__ hproj_w, const float* __restrict__ lm_w,
    const float* __restrict__ blob_mu, const float* __restrict__ blob_lv,
    const float* __restrict__ blob_ra, const float* __restrict__ blob_f,
    ushort_t* __restrict__ qpwbf, ushort_t* __restrict__ cwbf,
    ushort_t* __restrict__ hpwbf, ushort_t* __restrict__ wbf,
    float* __restrict__ cbias,
    float* __restrict__ mu, ushort_t* __restrict__ mub16,
    uint_t* __restrict__ muivP, float* __restrict__ alpha,
    float* __restrict__ feat, ushort_t* __restrict__ featb16,
    ushort_t* __restrict__ fTg, float* __restrict__ blobm,
    float* __restrict__ tres, float* __restrict__ qout) {
    int blk = blockIdx.x;
    int t = threadIdx.x;
    if (blk < NCVT_) {
        const float* s = nullptr; ushort_t* dd; int base; bool cw = false;
        if (blk < 8)        { s = qproj_w; dd = qpwbf; base = blk; }
        else if (blk < 52)  { dd = cwbf; base = blk - 8; cw = true; }
        else if (blk < 180) { s = hproj_w; dd = hpwbf; base = blk - 52; }
        else                { s = lm_w; dd = wbf; base = blk - 180; }
        #pragma unroll
        for (int k = 0; k < 4; ++k) {
            int i = base * 4096 + k * 1024 + t * 4;
            float4 v = {0.f, 0.f, 0.f, 0.f};
            if (cw) {
                int r = i >> 9, c = i & 511;
                if (r < 64)        v = *reinterpret_cast<const float4*>(mu_up_w + r * 512 + c);
                else if (r < 320)  v = *reinterpret_cast<const float4*>(ffn_w + (r - 64) * 512 + c);
                else if (r == 320) v = *reinterpret_cast<const float4*>(agate_w + c);
            } else {
                v = *reinterpret_cast<const float4*>(s + i);
            }
            ushort4 o = {f2bf(v.x), f2bf(v.y), f2bf(v.z), f2bf(v.w)};
            *reinterpret_cast<ushort4*>(dd + i) = o;
        }
        return;
    }
    if (blk < NGA_) {        // gather
        int row = blk - NCVT_;
        int l = row & (L_ - 1);
        int v = tok[row];
        if (t < DS_) {
            float m = tok_mu[(size_t)v * DS_ + t] + pos_mu[l * DS_ + t];
            mu[(size_t)row * DS_ + t] = m;
            mub16[(size_t)row * DS_ + t] = f2bf(m);
            float ivv = __expf(-tok_lv[(size_t)v * DS_ + t]);
            muivP[(size_t)t * BL_ + row] = packbf(m, ivv);
        }
        float fv = tok_f[(size_t)v * DF_ + t];
        feat[(size_t)row * DF_ + t] = fv;
        featb16[(size_t)row * DF_ + t] = f2bf(fv);
        int jb = (l >> 3) & 7, jr = l & 7;
        int jp = (l & ~63) | ((jb ^ (t & 7)) << 3) | jr;
        fTg[((size_t)((row >> 10) * DF_ + t) << 10) + jp] = f2bf(fv);
        if (t == 0) alpha[row] = sigmoidf_(tok_ra[v]);
        return;
    }
    if (blk < NST_) {        // query + blob
        __shared__ float red[256];
        __shared__ int stok[L_];
        __shared__ float sq[DS_];
        __shared__ float sa[NB_];
        __shared__ float sp[NB_];
        int b = blk - NGA_;
        for (int l = t; l < L_; l += 256) stok[l] = tok[b * L_ + l];
        __syncthreads();
        int d = t & 63, c = t >> 6;
        float s = 0.f;
        for (int l = c; l < L_; l += 4)
            s += tok_mu[(size_t)stok[l] * DS_ + d] + pos_mu[l * DS_ + d];
        red[t] = s;
        __syncthreads();
        if (c == 0)
            sq[d] = (red[d] + red[64 + d] + red[128 + d] + red[192 + d]) * (1.f / L_);
        __syncthreads();
        for (int n = t; n < NB_; n += 256) {
            float d2 = 0.f;
            for (int dd = 0; dd < DS_; ++dd) {
                float diff = sq[dd] - blob_mu[n * DS_ + dd];
                d2 += __expf(-blob_lv[n * DS_ + dd]) * diff * diff;
            }
            float a = sigmoidf_(blob_ra[n]) * __expf(-0.5f * d2);
            sa[n] = a;
            sp[n] = 1.f - a;
        }
        __syncthreads();
        int n0 = t, n1 = t + 256;
        for (int s2 = 1; s2 < NB_; s2 <<= 1) {
            float t0 = (n0 >= s2) ? sp[n0 - s2] : 1.f;
            float t1 = (n1 >= s2) ? sp[n1 - s2] : 1.f;
            __syncthreads();
            sp[n0] *= t0;
            sp[n1] *= t1;
            __syncthreads();
        }
        float w0 = sa[n0] * (n0 ? sp[n0 - 1] : 1.f);
        float w1 = sa[n1] * sp[n1 - 1];
        __syncthreads();
        sa[n0] = w0;
        sa[n1] = w1;
        if (t == 0) tres[b] = sp[NB_ - 1];
        __syncthreads();
        float acc = 0.f;
        for (int n = 0; n < NB_; ++n) acc += sa[n] * blob_f[n * DF_ + t];
        blobm[b * DF_ + t] = acc;
        return;
    }
    if (blk < NQP_) {        // combined bias (352)
        for (int idx = t; idx < 352; idx += 256) {
            float bv = 0.f;
            if (idx < 64) bv = mu_up_b[idx];
            else if (idx < 320) bv = ffn_b[idx - 64];
            else if (idx == 320) bv = agate_b[0];
            cbias[idx] = bv;
        }
        return;
    }
    // pass-0 qproj GEMM tile (self-gathered A; B from qproj_w f32, inline cvt)
    {
        __shared__ __align__(16) ushort_t sA[8][32][8];
        __shared__ __align__(16) ushort_t sB[8][32][8];
        int qi = blk - NQP_;
        int m0 = (qi & 63) * 32, n0 = (qi >> 6) * 32;
        int row = t >> 3, c8 = t & 7;
        {
            int grow = m0 + row;
            int l = grow & (L_ - 1);
            int v = tok[grow];
            const float* ms = tok_mu + (size_t)v * DS_ + c8 * 8;
            const float* ps = pos_mu + l * DS_ + c8 * 8;
            float4 m0v = *reinterpret_cast<const float4*>(ms);
            float4 m1v = *reinterpret_cast<const float4*>(ms + 4);
            float4 p0v = *reinterpret_cast<const float4*>(ps);
            float4 p1v = *reinterpret_cast<const float4*>(ps + 4);
            ushort_t* d = sA[c8][row];
            d[0] = f2bf(m0v.x + p0v.x); d[1] = f2bf(m0v.y + p0v.y);
            d[2] = f2bf(m0v.z + p0v.z); d[3] = f2bf(m0v.w + p0v.w);
            d[4] = f2bf(m1v.x + p1v.x); d[5] = f2bf(m1v.y + p1v.y);
            d[6] = f2bf(m1v.z + p1v.z); d[7] = f2bf(m1v.w + p1v.w);
            const float* wsrc = qproj_w + (size_t)(n0 + row) * DS_ + c8 * 8;
            float4 w0v = *reinterpret_cast<const float4*>(wsrc);
            float4 w1v = *reinterpret_cast<const float4*>(wsrc + 4);
            ushort_t* db = sB[c8][row];
            db[0] = f2bf(w0v.x); db[1] = f2bf(w0v.y);
            db[2] = f2bf(w0v.z); db[3] = f2bf(w0v.w);
            db[4] = f2bf(w1v.x); db[5] = f2bf(w1v.y);
            db[6] = f2bf(w1v.z); db[7] = f2bf(w1v.w);
        }
        __syncthreads();
        int wv = t >> 6, lane = t & 63;
        int wr = wv >> 1, wc = wv & 1;
        int lr = lane & 15, q4 = lane >> 4;
        f32x4 qa = {};
        #pragma unroll
        for (int kk = 0; kk < 2; ++kk) {
            bf16x8 af = *reinterpret_cast<const bf16x8*>(sA[kk * 4 + q4][wr * 16 + lr]);
            bf16x8 bf_ = *reinterpret_cast<const bf16x8*>(sB[kk * 4 + q4][wc * 16 + lr]);
            qa = __builtin_amdgcn_mfma_f32_16x16x32_bf16(af, bf_, qa, 0, 0, 0);
        }
        int ocol = n0 + wc * 16 + lr;
        float bv = qproj_b[ocol];
        #pragma unroll
        for (int j = 0; j < 4; ++j) {
            int orow = m0 + wr * 16 + q4 * 4 + j;
            qout[(size_t)orow * 512 + ocol] = qa[j] + bv;
        }
    }
}

// ---------------------------------------------------------------------------
// Attention v7: TWO rows (i0, i0+1) per 512-thread block (r11/r12, verified).
__global__ __launch_bounds__(512) void k_attn7(
    const float* __restrict__ q, const uint_t* __restrict__ muivP,
    const float* __restrict__ alpha, const ushort_t* __restrict__ fTg,
    ushort_t* __restrict__ mcatb) {
    __shared__ __align__(16) uint_t smiu[64 * 64];      // [d][jl]  16 KB
    __shared__ __align__(16) ushort_t sfT[256 * 64];    // [c][j']  32 KB
    __shared__ __align__(16) ushort_t sw16[16][72];     // A-tile (16 live rows)
    __shared__ float sqA[512], sqB[512];
    __shared__ float sT[16];
    int tid = threadIdx.x;
    int w = tid >> 6, lane = tid & 63;
    int bid = blockIdx.x;
    int b = bid >> 9;
    int i0 = (bid & 511) * 2, i1 = i0 + 1;
    int row0 = b * L_ + i0;
    const int lr = lane & 15, q4 = lane >> 4;

    sqA[tid] = q[(size_t)row0 * 512 + tid];
    sqB[tid] = q[(size_t)(row0 + 1) * 512 + tid];

    float T0 = 1.f, T1 = 1.f;
    f32x4 acc0 = {}, acc1 = {};

    for (int j0 = 0; j0 <= i1; j0 += 64) {
        __syncthreads();   // publish sq/sT; protect prev-chunk LDS
        if (j0 > 0) {
            bool alive = false;
            #pragma unroll
            for (int h = 0; h < 16; ++h) alive |= (sT[h] >= 1e-12f);
            if (!alive) break;
        }
        // stage muiv chunk (wave w covers d rows w*8..w*8+7)
        {
            const uint_t* src = muivP + b * L_ + j0;
            #pragma unroll
            for (int r = 0; r < 2; ++r) {
                int d = w * 8 + r * 4 + q4;
                const uint_t* gp = src + (size_t)d * BL_ + lr * 4;
                __builtin_amdgcn_global_load_lds((const AS1 uint_t*)gp,
                    (AS3 uint_t*)&smiu[(w * 8 + r * 4) * 64], 16, 0, 0);
            }
        }
        // stage feature chunk K-major: wave w covers c rows w*32..w*32+31
        {
            #pragma unroll
            for (int it = 0; it < 4; ++it) {
                int c0 = w * 32 + it * 8;
                const ushort_t* gp = fTg +
                    ((size_t)(b * DF_ + c0 + (lane >> 3)) << 10) + j0 + (lane & 7) * 8;
                __builtin_amdgcn_global_load_lds((const AS1 uint_t*)gp,
                    (AS3 uint_t*)&sfT[c0 * 64], 16, 0, 0);
            }
        }
        __syncthreads();   // stage landed

        // phase A: d2 for both rows (shared LDS read)
        int jj = j0 + lane;
        int jc = jj <= i1 ? jj : i1;
        float alv = alpha[b * L_ + jc];
        float d20 = 0.f, d21 = 0.f;
        #pragma unroll 8
        for (int d = 0; d < 64; ++d) {
            uint_t v = smiu[d * 64 + lane];
            float m = bflo(v), iv = bfhi(v);
            float f0 = sqA[w * 64 + d] - m;
            float f1 = sqB[w * 64 + d] - m;
            d20 = fmaf(iv * f0, f0, d20);
            d21 = fmaf(iv * f1, f1, d21);
        }
        float a0 = (jj <= i0) ? alv * __expf(-0.5f * d20) : 0.f;
        float a1 = (jj <= i1) ? alv * __expf(-0.5f * d21) : 0.f;

        // phase B: two wave product-scans
        float p = 1.f - a0;
        #pragma unroll
        for (int s = 1; s < 64; s <<= 1) {
            float tt = __shfl_up(p, s, 64);
            if (lane >= s) p *= tt;
        }
        float Tex = __shfl_up(p, 1, 64);
        if (lane == 0) Tex = 1.f;
        sw16[w][lane] = f2bf(a0 * T0 * Tex);
        T0 *= __shfl(p, 63, 64);

        p = 1.f - a1;
        #pragma unroll
        for (int s = 1; s < 64; s <<= 1) {
            float tt = __shfl_up(p, s, 64);
            if (lane >= s) p *= tt;
        }
        Tex = __shfl_up(p, 1, 64);
        if (lane == 0) Tex = 1.f;
        sw16[w + 8][lane] = f2bf(a1 * T1 * Tex);
        T1 *= __shfl(p, 63, 64);

        if (lane == 0) { sT[w] = T0; sT[w + 8] = T1; }
        __syncthreads();   // sw16 complete

        // phase C: PV via MFMA (wave w owns col tiles 2w, 2w+1; A fully live)
        #pragma unroll
        for (int kk = 0; kk < 2; ++kk) {
            bf16x8 afr = *reinterpret_cast<const bf16x8*>(
                (const char*)sw16 + lr * 144 + kk * 64 + q4 * 16);
            {
                int c = (w * 2 + 0) * 16 + lr;
                int bo = c * 128 + ((kk * 64 + q4 * 16) ^ ((c & 7) << 4));
                bf16x8 bfr = *reinterpret_cast<const bf16x8*>((const char*)sfT + bo);
                acc0 = __builtin_amdgcn_mfma_f32_16x16x32_bf16(afr, bfr, acc0, 0, 0, 0);
            }
            {
                int c = (w * 2 + 1) * 16 + lr;
                int bo = c * 128 + ((kk * 64 + q4 * 16) ^ ((c & 7) << 4));
                bf16x8 bfr = *reinterpret_cast<const bf16x8*>((const char*)sfT + bo);
                acc1 = __builtin_amdgcn_mfma_f32_16x16x32_bf16(afr, bfr, acc1, 0, 0, 0);
            }
        }
    }
    // epilogue: C row r -> head r&7, row-parity r>>3
    #pragma unroll
    for (int j = 0; j < 4; ++j) {
        int r = q4 * 4 + j;
        int h = r & 7, par = r >> 3;
        size_t rw = (size_t)(row0 + par) * 2048 + h * 256;
        mcatb[rw + (w * 2 + 0) * 16 + lr] = f2bf(acc0[j]);
        mcatb[rw + (w * 2 + 1) * 16 + lr] = f2bf(acc1[j]);
    }
}

// ---------------------------------------------------------------------------
// bf16 MFMA GEMM with optional XCD swizzle (SWZ) and optional fused APPLY
// epilogue (column-local k_apply update regions).
template <int BM, int BN, int BK, int WGM, int WGN, bool NTS, bool WB16,
          bool SWZ, bool APPLY>
__global__ __launch_bounds__(256) void gemm_mfma2(
    const ushort_t* __restrict__ A, const ushort_t* __restrict__ A2, int K1,
    int strideA, const ushort_t* __restrict__ W, const float* __restrict__ bias,
    float* __restrict__ C, ushort_t* __restrict__ Cb, int M, int N, int K,
    float* __restrict__ muP, ushort_t* __restrict__ mub16P,
    uint_t* __restrict__ muivPP, float* __restrict__ alphaP,
    float* __restrict__ featP, ushort_t* __restrict__ featb16P,
    ushort_t* __restrict__ fTgP) {
    constexpr int WMF = BM / WGM / 16;
    constexpr int WNF = BN / WGN / 16;
    constexpr int KK  = BK / 32;
    constexpr int AHALF = BM * BK;
    constexpr int BHALF = BN * BK;
    constexpr int STAGE_B = 2 * (AHALF + BHALF) * 2;
    constexpr int EPI_B = BM * BN * 4;
    constexpr int SMEM_B = STAGE_B > EPI_B ? STAGE_B : EPI_B;
    __shared__ __align__(16) char smem[SMEM_B];
    ushort_t* As = (ushort_t*)smem;
    ushort_t* Bs = (ushort_t*)(smem + 2 * AHALF * 2);

    const int tid = threadIdx.x;
    const int wave = tid >> 6, lane = tid & 63;
    int bx = blockIdx.x, by = blockIdx.y;
    if (SWZ) {
        int nwg = gridDim.x * gridDim.y;
        int lin = by * gridDim.x + bx;
        int q = nwg >> 3, r = nwg & 7;
        int xcd = lin & 7, idx = lin >> 3;
        int nl = (xcd < r) ? (xcd * (q + 1) + idx)
                           : (r * (q + 1) + (xcd - r) * q + idx);
        bx = nl % gridDim.x;
        by = nl / gridDim.x;
    }
    const int m0 = bx * BM, n0 = by * BN;
    const int wr = wave / WGN, wc = wave % WGN;
    const int lr = lane & 15;
    const int q4 = lane >> 4;

    f32x4 acc[WMF][WNF] = {};

    auto stage = [&](int buf, int t) {
        const int k0g = t * BK;
        const ushort_t* Abase = (A2 != nullptr && k0g >= K1) ? A2 : A;
        const int kof = (A2 != nullptr && k0g >= K1) ? k0g - K1 : k0g;
        ushort_t* Ad = As + buf * AHALF;
        #pragma unroll
        for (int it = 0; it < (BM * BK / 8) / 256; ++it) {
            int cbase = it * 256 + wave * 64;
            int c = cbase + lane;
            int r = c & (BM - 1), c8 = c / BM;
            const ushort_t* gp = Abase + (size_t)(m0 + r) * strideA + kof + c8 * 8;
            __builtin_amdgcn_global_load_lds((const AS1 uint_t*)gp,
                                             (AS3 uint_t*)(Ad + cbase * 8), 16, 0, 0);
        }
        ushort_t* Bd = Bs + buf * BHALF;
        #pragma unroll
        for (int it = 0; it < (BN * BK / 8) / 256; ++it) {
            int cbase = it * 256 + wave * 64;
            int c = cbase + lane;
            int r = c & (BN - 1), c8 = c / BN;
            const ushort_t* gp = W + (size_t)(n0 + r) * K + k0g + c8 * 8;
            __builtin_amdgcn_global_load_lds((const AS1 uint_t*)gp,
                                             (AS3 uint_t*)(Bd + cbase * 8), 16, 0, 0);
        }
    };

    const int nsteps = K / BK;
    stage(0, 0);
    __syncthreads();
    for (int t = 0; t < nsteps; ++t) {
        const int cur = t & 1;
        if (t + 1 < nsteps) stage(cur ^ 1, t + 1);
        const ushort_t* Ab = As + cur * AHALF;
        const ushort_t* Bb = Bs + cur * BHALF;
        bf16x8 af[WMF][KK], bfr[WNF][KK];
        #pragma unroll
        for (int mi = 0; mi < WMF; ++mi)
            #pragma unroll
            for (int kk = 0; kk < KK; ++kk)
                af[mi][kk] = *reinterpret_cast<const bf16x8*>(
                    &Ab[((kk * 4 + q4) * BM + wr * (BM / WGM) + mi * 16 + lr) * 8]);
        #pragma unroll
        for (int ni = 0; ni < WNF; ++ni)
            #pragma unroll
            for (int kk = 0; kk < KK; ++kk)
                bfr[ni][kk] = *reinterpret_cast<const bf16x8*>(
                    &Bb[((kk * 4 + q4) * BN + wc * (BN / WGN) + ni * 16 + lr) * 8]);
        #pragma unroll
        for (int kk = 0; kk < KK; ++kk)
            #pragma unroll
            for (int mi = 0; mi < WMF; ++mi)
                #pragma unroll
                for (int ni = 0; ni < WNF; ++ni)
                    acc[mi][ni] = __builtin_amdgcn_mfma_f32_16x16x32_bf16(
                        af[mi][kk], bfr[ni][kk], acc[mi][ni], 0, 0, 0);
        __syncthreads();
    }

    float* tile = (float*)smem;
    #pragma unroll
    for (int mi = 0; mi < WMF; ++mi)
        #pragma unroll
        for (int ni = 0; ni < WNF; ++ni) {
            int col = wc * (BN / WGN) + ni * 16 + lr;
            float bv = bias[n0 + col];
            #pragma unroll
            for (int j = 0; j < 4; ++j) {
                int r2 = wr * (BM / WGM) + mi * 16 + q4 * 4 + j;
                tile[r2 * BN + col] = acc[mi][ni][j] + bv;
            }
        }
    __syncthreads();
    constexpr int EV = (BM * BN / 4) / 256;
    #pragma unroll
    for (int e = 0; e < EV; ++e) {
        int idx = e * 256 + tid;
        int r = idx / (BN / 4), c4 = idx % (BN / 4);
        f32x4 v = reinterpret_cast<const f32x4*>(tile)[idx];
        if (APPLY) {
            int row = m0 + r;
            int col0 = n0 + c4 * 4;
            if (col0 < 64) {               // dmu region
                #pragma unroll
                for (int k = 0; k < 4; ++k) {
                    int d = col0 + k;
                    float m = muP[(size_t)row * DS_ + d] + v[k];
                    muP[(size_t)row * DS_ + d] = m;
                    mub16P[(size_t)row * DS_ + d] = f2bf(m);
                    size_t ix = (size_t)d * BL_ + row;
                    uint_t old = muivPP[ix];
                    muivPP[ix] = (old & 0xFFFF0000u) | (uint_t)f2bf(m);
                }
            } else if (col0 < 320) {       // dffn region
                int l = row & (L_ - 1);
                int bb = row >> 10;
                int jb = (l >> 3) & 7, jr = l & 7;
                #pragma unroll
                for (int k = 0; k < 4; ++k) {
                    int fc = col0 + k - 64;
                    float fn = featP[(size_t)row * DF_ + fc] + v[k];
                    featP[(size_t)row * DF_ + fc] = fn;
                    featb16P[(size_t)row * DF_ + fc] = f2bf(fn);
                    int jp = (l & ~63) | ((jb ^ (fc & 7)) << 3) | jr;
                    fTgP[((size_t)(bb * DF_ + fc) << 10) + jp] = f2bf(fn);
                }
            } else {                       // gate region (col 320 only)
                #pragma unroll
                for (int k = 0; k < 4; ++k)
                    if (col0 + k == 320) alphaP[row] *= sigmoidf_(v[k]);
            }
        } else {
            f32x4* dst = reinterpret_cast<f32x4*>(&C[(size_t)(m0 + r) * N + n0 + c4 * 4]);
            if (NTS) __builtin_nontemporal_store(v, dst);
            else *dst = v;
            if (WB16) {
                ushort4 ob = {f2bf(v[0]), f2bf(v[1]), f2bf(v[2]), f2bf(v[3])};
                *reinterpret_cast<ushort4*>(&Cb[(size_t)(m0 + r) * N + n0 + c4 * 4]) = ob;
            }
        }
    }
}

// gate + fuse + layernorm -> bf16 h.  grid BL_
__global__ __launch_bounds__(256) void k_fused_ln(
    const float* __restrict__ meaning, const float* __restrict__ blobm,
    const float* __restrict__ tres, const float* __restrict__ bgw,
    const float* __restrict__ bgb, const float* __restrict__ ln_g,
    const float* __restrict__ ln_b, ushort_t* __restrict__ houtb) {
    __shared__ float red[256];
    int row = blockIdx.x, t = threadIdx.x;
    int b = row >> 10;
    float m = meaning[(size_t)row * DF_ + t];
    float be = blobm[b * DF_ + t];
    float tr = tres[b];
    float gsum = block_reduce_sum(be * bgw[t] + m * bgw[256 + t], red);
    float gate = sigmoidf_(gsum + bgb[0]);
    float f = (1.f - tr) * gate * be + tr * m;
    float mean = block_reduce_sum(f, red) * (1.f / DF_);
    float d = f - mean;
    float var = block_reduce_sum(d * d, red) * (1.f / DF_);
    houtb[(size_t)row * DF_ + t] = f2bf(d * rsqrtf(var + EPS_) * ln_g[t] + ln_b[t]);
}

extern "C" void kernel_launch(void* const* d_in, const int* in_sizes, int n_in,
                              void* d_out, int out_size, void* d_ws, size_t ws_size,
                              hipStream_t stream) {
    const int*   tok      = (const int*)d_in[0];
    const float* tok_mu   = (const float*)d_in[1];
    const float* tok_lv   = (const float*)d_in[2];
    const float* tok_ra   = (const float*)d_in[3];
    const float* tok_f    = (const float*)d_in[4];
    const float* pos_mu   = (const float*)d_in[5];
    const float* qproj_w  = (const float*)d_in[6];
    const float* qproj_b  = (const float*)d_in[7];
    const float* hproj_w  = (const float*)d_in[8];
    const float* hproj_b  = (const float*)d_in[9];
    const float* mu_up_w  = (const float*)d_in[10];
    const float* mu_up_b  = (const float*)d_in[11];
    const float* agate_w  = (const float*)d_in[12];
    const float* agate_b  = (const float*)d_in[13];
    const float* ffn_w    = (const float*)d_in[14];
    const float* ffn_b    = (const float*)d_in[15];
    const float* ln_g     = (const float*)d_in[16];
    const float* ln_b     = (const float*)d_in[17];
    const float* lm_w     = (const float*)d_in[18];
    const float* lm_b     = (const float*)d_in[19];
    const float* blob_mu  = (const float*)d_in[20];
    const float* blob_lv  = (const float*)d_in[21];
    const float* blob_ra  = (const float*)d_in[22];
    const float* blob_f   = (const float*)d_in[23];
    const float* bgate_w  = (const float*)d_in[24];
    const float* bgate_b  = (const float*)d_in[25];
    float* out = (float*)d_out;

    float* ws = (float*)d_ws;
    float* mu      = ws;                        // BL*64
    float* alpha   = mu + BL_ * DS_;            // BL
    float* feat    = alpha + BL_;               // BL*256
    float* blobm   = feat + BL_ * DF_;          // B*256
    float* tres    = blobm + B_ * DF_;          // pad 64
    float* q       = tres + 64;                 // BL*512
    float* meaning = q + BL_ * 512;             // BL*256
    float* cbias   = meaning + BL_ * DF_;       // 352 (pad 384)
    uint_t* muivP  = (uint_t*)(cbias + 384);              // 64*BL
    ushort_t* fTg   = (ushort_t*)(muivP + (size_t)DS_ * BL_); // B*256*1024
    ushort_t* mub16 = fTg + (size_t)B_ * DF_ * L_;        // BL*64
    ushort_t* featb16 = mub16 + (size_t)BL_ * DS_;        // BL*256
    ushort_t* meanb16 = featb16 + (size_t)BL_ * DF_;      // BL*256
    ushort_t* mcatb = meanb16 + (size_t)BL_ * DF_;        // BL*2048
    ushort_t* hbufb = mcatb + (size_t)BL_ * 2048;         // BL*256
    ushort_t* wbf   = hbufb + (size_t)BL_ * DF_;          // V*256
    ushort_t* hpwbf = wbf + (size_t)V_ * DF_;             // 256*2048
    ushort_t* qpwbf = hpwbf + (size_t)DF_ * 2048;         // 512*64
    ushort_t* cwbf  = qpwbf + (size_t)512 * 64;           // 352*512

    k_setup<<<NTOT_, 256, 0, stream>>>(
        tok, tok_mu, tok_lv, tok_ra, tok_f, pos_mu,
        qproj_w, qproj_b, mu_up_w, mu_up_b, ffn_w, ffn_b, agate_w, agate_b,
        hproj_w, lm_w, blob_mu, blob_lv, blob_ra, blob_f,
        qpwbf, cwbf, hpwbf, wbf, cbias,
        mu, mub16, muivP, alpha, feat, featb16, fTg, blobm, tres, q);

    // pass 0 (qproj already done inside k_setup)
    k_attn7<<<B_ * L_ / 2, 512, 0, stream>>>(q, muivP, alpha, fTg, mcatb);
    gemm_mfma2<32, 32, 128, 2, 2, false, true, false, false>
        <<<dim3(BL_ / 32, DF_ / 32), 256, 0, stream>>>(
        mcatb, nullptr, 0, H_ * DF_, hpwbf, hproj_b, meaning, meanb16,
        BL_, DF_, H_ * DF_,
        nullptr, nullptr, nullptr, nullptr, nullptr, nullptr, nullptr);
    gemm_mfma2<32, 32, 128, 2, 2, false, false, false, true>
        <<<dim3(BL_ / 32, 352 / 32), 256, 0, stream>>>(
        featb16, meanb16, DF_, DF_, cwbf, cbias, nullptr, nullptr,
        BL_, 352, 512,
        mu, mub16, muivP, alpha, feat, featb16, fTg);

    // pass 1
    gemm_mfma2<32, 32, 64, 2, 2, false, false, false, false>
        <<<dim3(BL_ / 32, 512 / 32), 256, 0, stream>>>(
        mub16, nullptr, 0, DS_, qpwbf, qproj_b, q, nullptr, BL_, 512, DS_,
        nullptr, nullptr, nullptr, nullptr, nullptr, nullptr, nullptr);
    k_attn7<<<B_ * L_ / 2, 512, 0, stream>>>(q, muivP, alpha, fTg, mcatb);
    gemm_mfma2<32, 32, 128, 2, 2, false, false, false, false>
        <<<dim3(BL_ / 32, DF_ / 32), 256, 0, stream>>>(
        mcatb, nullptr, 0, H_ * DF_, hpwbf, hproj_b, meaning, nullptr,
        BL_, DF_, H_ * DF_,
        nullptr, nullptr, nullptr, nullptr, nullptr, nullptr, nullptr);

    k_fused_ln<<<BL_, 256, 0, stream>>>(meaning, blobm, tres, bgate_w, bgate_b,
                                        ln_g, ln_b, hbufb);
    gemm_mfma2<128, 128, 64, 2, 2, true, false, true, false>
        <<<dim3(BL_ / 128, V_ / 128), 256, 0, stream>>>(
        hbufb, nullptr, 0, DF_, wbf, lm_b, out, nullptr, BL_, V_, DF_,
        nullptr, nullptr, nullptr, nullptr, nullptr, nullptr, nullptr);
}